// Round 2
// baseline (1606.103 us; speedup 1.0000x reference)
//
#include <hip/hip_runtime.h>
#include <cstdint>
#include <cstddef>

#define N_NODES 40000
#define DIN     386
#define H1      256
#define NREL    16
#define KPAD    416      // 13*32: zero-padded K for layer-1 GEMM
#define MPAD    40064    // 313*128: zero-padded M
#define NB1     17       // 16 relation blocks + 1 root block, 256 cols each
#define NCOLS1  (NB1 * H1)      // 4352
#define Y2C     (2 * NREL + 2)  // 34

typedef __attribute__((ext_vector_type(8))) short s8v;
typedef __attribute__((ext_vector_type(4))) float f4v;

__device__ __forceinline__ float bf2f(uint16_t v) {
  return __uint_as_float(((uint32_t)v) << 16);
}
__device__ __forceinline__ uint16_t f2bf(float f) {  // RNE
  uint32_t u = __float_as_uint(f);
  u += 0x7FFF + ((u >> 16) & 1);
  return (uint16_t)(u >> 16);
}
// inline asm MFMA (verified working in round 1: numerics matched to bf16 level)
__device__ __forceinline__ f4v mfma_bf16(s8v a, s8v b, f4v c) {
  asm("v_mfma_f32_16x16x32_bf16 %0, %1, %2, %0" : "+v"(c) : "v"(a), "v"(b));
  return c;
}

__device__ __forceinline__ void gload16(const uint16_t* g, uint16_t* lds) {
  __builtin_amdgcn_global_load_lds(
      (const __attribute__((address_space(1))) unsigned int*)g,
      (__attribute__((address_space(3))) unsigned int*)lds, 16, 0, 0);
}

// ---------- CSR build ----------
__global__ void k_count(const int* __restrict__ dst, const int* __restrict__ et,
                        int* __restrict__ deg, int* __restrict__ cnt, int E) {
  int e = blockIdx.x * 256 + threadIdx.x;
  if (e < E) {
    int d = dst[e], r = et[e];
    atomicAdd(&deg[d], 1);
    atomicAdd(&cnt[r * N_NODES + d], 1);
  }
}

__global__ void k_scan(const int* __restrict__ deg, int* __restrict__ rowptr) {
  __shared__ int sd[1024];
  __shared__ int s_carry;
  int tid = threadIdx.x;
  if (tid == 0) { s_carry = 0; rowptr[0] = 0; }
  __syncthreads();
  for (int base = 0; base < N_NODES; base += 1024) {
    int v = (base + tid < N_NODES) ? deg[base + tid] : 0;
    sd[tid] = v;
    __syncthreads();
    for (int off = 1; off < 1024; off <<= 1) {
      int t = (tid >= off) ? sd[tid - off] : 0;
      __syncthreads();
      sd[tid] += t;
      __syncthreads();
    }
    int incl = sd[tid];
    int carry = s_carry;
    if (base + tid < N_NODES) rowptr[base + tid + 1] = carry + incl;
    __syncthreads();
    if (tid == 1023) s_carry = carry + sd[1023];
    __syncthreads();
  }
}

__global__ void k_scatter(const int* __restrict__ src, const int* __restrict__ dst,
                          const int* __restrict__ et, const int* __restrict__ rowptr,
                          int* __restrict__ cursor, const int* __restrict__ cnt,
                          int* __restrict__ es_src, int* __restrict__ es_rel,
                          float* __restrict__ es_w, int E) {
  int e = blockIdx.x * 256 + threadIdx.x;
  if (e < E) {
    int d = dst[e], r = et[e], s = src[e];
    int pos = atomicAdd(&cursor[d], 1);
    int idx = rowptr[d] + pos;
    es_src[idx] = s;
    es_rel[idx] = r;
    es_w[idx] = 1.0f / (float)cnt[r * N_NODES + d];
  }
}

// ---------- packs: split each fp32 value into hi/lo bf16 ----------
__global__ void k_pack_x(const float* __restrict__ x, uint16_t* __restrict__ xh,
                         uint16_t* __restrict__ xl) {
  long long i = (long long)blockIdx.x * 256 + threadIdx.x;
  if (i >= (long long)MPAD * KPAD) return;
  int n = (int)(i / KPAD), k = (int)(i % KPAD);
  float v = (n < N_NODES && k < DIN) ? x[(long long)n * DIN + k] : 0.0f;
  uint16_t h = f2bf(v);
  xh[i] = h;
  xl[i] = f2bf(v - bf2f(h));
}

__global__ void k_pack_b1(const float* __restrict__ W1, const float* __restrict__ root1,
                          uint16_t* __restrict__ Bh, uint16_t* __restrict__ Bl) {
  long long i = (long long)blockIdx.x * 256 + threadIdx.x;
  if (i >= (long long)NCOLS1 * KPAD) return;
  int c = (int)(i / KPAD), k = (int)(i % KPAD);
  float v = 0.0f;
  if (k < DIN) {
    if (c < NREL * H1) {
      int r = c >> 8, j = c & 255;
      v = W1[((long long)r * DIN + k) * H1 + j];
    } else {
      v = root1[(long long)k * H1 + (c - NREL * H1)];
    }
  }
  uint16_t h = f2bf(v);
  Bh[i] = h;
  Bl[i] = f2bf(v - bf2f(h));
}

__global__ void k_pack_b2(const float* __restrict__ W2, const float* __restrict__ root2,
                          float* __restrict__ B2t) {
  int i = blockIdx.x * 256 + threadIdx.x;
  if (i >= Y2C * H1) return;
  int c = i / H1, k = i % H1;
  float v;
  if (c < 2 * NREL) { int r = c >> 1, j = c & 1; v = W2[(r * H1 + k) * 2 + j]; }
  else v = root2[k * 2 + (c - 2 * NREL)];
  B2t[i] = v;
}

// ---------- layer-1 GEMM (split bf16): C[m,c] = sum_k A[m,k]*B[c,k], fp32 out ----------
__global__ __launch_bounds__(256) void k_gemm1(
    const uint16_t* __restrict__ Ah, const uint16_t* __restrict__ Al,
    const uint16_t* __restrict__ Bh, const uint16_t* __restrict__ Bl,
    float* __restrict__ C, int ldc) {
  // 4 tiles of [128 rows][32 k] bf16 = 8KB each
  __shared__ __align__(16) uint16_t sAh[128 * 32];
  __shared__ __align__(16) uint16_t sAl[128 * 32];
  __shared__ __align__(16) uint16_t sBh[128 * 32];
  __shared__ __align__(16) uint16_t sBl[128 * 32];
  int tid = threadIdx.x;
  int lane = tid & 63, w = tid >> 6;
  int wr = w >> 1, wc = w & 1;
  long long bm = (long long)blockIdx.x * 128;
  long long bn = (long long)blockIdx.y * 128;

  f4v zero = {0.f, 0.f, 0.f, 0.f};
  f4v acc[4][4];
#pragma unroll
  for (int i = 0; i < 4; ++i)
#pragma unroll
    for (int j = 0; j < 4; ++j) acc[i][j] = zero;

  int lrow = lane & 15, lk = (lane >> 4) * 8;
  // staging geometry: wave w covers LDS bytes [w*2048, w*2048+2048) of each 8KB tile,
  // two 1KB instructions; lane l covers row = (p>>6), kbyte = p&63, p = instbase + l*16
  int srow0 = w * 32 + (lane >> 2);      // inst 0: rows w*32 .. w*32+15
  int srow1 = srow0 + 16;                // inst 1
  int skel = (lane & 3) * 8;             // k-element offset (16B = 8 elems)

  for (int kk = 0; kk < KPAD; kk += 32) {
    const uint16_t* gA0 = Ah + (bm + srow0) * KPAD + kk + skel;
    const uint16_t* gA1 = Ah + (bm + srow1) * KPAD + kk + skel;
    const uint16_t* gAl0 = Al + (bm + srow0) * KPAD + kk + skel;
    const uint16_t* gAl1 = Al + (bm + srow1) * KPAD + kk + skel;
    const uint16_t* gB0 = Bh + (bn + srow0) * KPAD + kk + skel;
    const uint16_t* gB1 = Bh + (bn + srow1) * KPAD + kk + skel;
    const uint16_t* gBl0 = Bl + (bn + srow0) * KPAD + kk + skel;
    const uint16_t* gBl1 = Bl + (bn + srow1) * KPAD + kk + skel;
    gload16(gA0, sAh + w * 1024);
    gload16(gA1, sAh + w * 1024 + 512);
    gload16(gAl0, sAl + w * 1024);
    gload16(gAl1, sAl + w * 1024 + 512);
    gload16(gB0, sBh + w * 1024);
    gload16(gB1, sBh + w * 1024 + 512);
    gload16(gBl0, sBl + w * 1024);
    gload16(gBl1, sBl + w * 1024 + 512);
    __syncthreads();   // drains vmcnt: staged data visible

    s8v ah[4], al[4];
#pragma unroll
    for (int mi = 0; mi < 4; ++mi) {
      ah[mi] = *(const s8v*)(sAh + (wr * 64 + mi * 16 + lrow) * 32 + lk);
      al[mi] = *(const s8v*)(sAl + (wr * 64 + mi * 16 + lrow) * 32 + lk);
    }
#pragma unroll
    for (int ni = 0; ni < 4; ++ni) {
      s8v bh = *(const s8v*)(sBh + (wc * 64 + ni * 16 + lrow) * 32 + lk);
      s8v bl = *(const s8v*)(sBl + (wc * 64 + ni * 16 + lrow) * 32 + lk);
#pragma unroll
      for (int mi = 0; mi < 4; ++mi) {
        acc[mi][ni] = mfma_bf16(ah[mi], bh, acc[mi][ni]);
        acc[mi][ni] = mfma_bf16(al[mi], bh, acc[mi][ni]);
        acc[mi][ni] = mfma_bf16(ah[mi], bl, acc[mi][ni]);
      }
    }
    __syncthreads();   // protect LDS before next stage
  }
  // C/D layout: col = lane&15, row = (lane>>4)*4 + reg
  int rg = (lane >> 4) * 4;
#pragma unroll
  for (int mi = 0; mi < 4; ++mi) {
#pragma unroll
    for (int ni = 0; ni < 4; ++ni) {
      long long col = bn + wc * 64 + ni * 16 + (lane & 15);
#pragma unroll
      for (int r = 0; r < 4; ++r) {
        long long row = bm + wr * 64 + mi * 16 + rg + r;
        C[row * ldc + col] = acc[mi][ni][r];
      }
    }
  }
}

// ---------- aggregation 1: h[n,c] += sum_e w_e * y1[src_e, rel_e*256+c] (+ root) ----------
__global__ void k_agg1(const float* __restrict__ y1,
                       const int* __restrict__ es_src, const int* __restrict__ es_rel,
                       const float* __restrict__ es_w, const int* __restrict__ rowptr,
                       float* __restrict__ h, int r0, int nb, int ldy) {
  int n = blockIdx.x;
  int c = threadIdx.x;
  float acc = h[(long long)n * H1 + c];
  int e0 = rowptr[n], e1 = rowptr[n + 1];
  int rhi = r0 + nb;
  for (int e = e0; e < e1; ++e) {
    int r = es_rel[e];
    if (r >= r0 && r < rhi) {
      int s = es_src[e];
      float wgt = es_w[e];
      acc += wgt * y1[(long long)s * ldy + (r - r0) * H1 + c];
    }
  }
  if (r0 <= NREL && NREL < rhi)  // root block (index 16) in this chunk
    acc += y1[(long long)n * ldy + (NREL - r0) * H1 + c];
  h[(long long)n * H1 + c] = acc;
}

__global__ void k_fin1(float* __restrict__ h, const float* __restrict__ b1) {
  long long i = (long long)blockIdx.x * 256 + threadIdx.x;
  if (i >= (long long)N_NODES * H1) return;
  int c = (int)(i & 255);
  float v = h[i] + b1[c];
  h[i] = v > 0.f ? v : 0.f;   // relu, in place (fp32 feeds layer 2)
}

// ---------- layer-2 transform (fp32 vector; tiny) ----------
__global__ void k_gemm2(const float* __restrict__ h, const float* __restrict__ B2t,
                        float* __restrict__ y2) {
  int o = blockIdx.x * 256 + threadIdx.x;
  if (o >= N_NODES * Y2C) return;
  int n = o / Y2C, c = o % Y2C;
  const float4* hr = (const float4*)(h + (long long)n * H1);
  const float4* br = (const float4*)(B2t + c * H1);
  float acc = 0.f;
#pragma unroll 8
  for (int i = 0; i < H1 / 4; ++i) {
    float4 a = hr[i], b = br[i];
    acc += a.x * b.x + a.y * b.y + a.z * b.z + a.w * b.w;
  }
  y2[o] = acc;
}

// ---------- aggregation 2 + tanh ----------
__global__ void k_agg2(const float* __restrict__ y2, const int* __restrict__ es_src,
                       const int* __restrict__ es_rel, const float* __restrict__ es_w,
                       const int* __restrict__ rowptr, const float* __restrict__ b2,
                       float* __restrict__ out) {
  int n = blockIdx.x * 4 + (threadIdx.x >> 6);
  int lane = threadIdx.x & 63;
  if (n >= N_NODES) return;
  float a0 = 0.f, a1 = 0.f;
  int e0 = rowptr[n], e1 = rowptr[n + 1];
  for (int e = e0 + lane; e < e1; e += 64) {
    int s = es_src[e], r = es_rel[e];
    float wgt = es_w[e];
    a0 += wgt * y2[s * Y2C + r * 2];
    a1 += wgt * y2[s * Y2C + r * 2 + 1];
  }
#pragma unroll
  for (int off = 32; off > 0; off >>= 1) {
    a0 += __shfl_down(a0, off);
    a1 += __shfl_down(a1, off);
  }
  if (lane == 0) {
    a0 += y2[n * Y2C + 2 * NREL] + b2[0];
    a1 += y2[n * Y2C + 2 * NREL + 1] + b2[1];
    out[n * 2] = tanhf(a0);
    out[n * 2 + 1] = tanhf(a1);
  }
}

extern "C" void kernel_launch(void* const* d_in, const int* in_sizes, int n_in,
                              void* d_out, int out_size, void* d_ws, size_t ws_size,
                              hipStream_t stream) {
  const float* x     = (const float*)d_in[0];
  const int*   ei    = (const int*)d_in[1];
  const int*   et    = (const int*)d_in[2];
  const float* W1    = (const float*)d_in[3];
  const float* root1 = (const float*)d_in[4];
  const float* b1    = (const float*)d_in[5];
  const float* W2    = (const float*)d_in[6];
  const float* root2 = (const float*)d_in[7];
  const float* b2    = (const float*)d_in[8];
  const int E = in_sizes[2];
  const int* src = ei;
  const int* dst = ei + E;

  char* ws = (char*)d_ws;
  size_t off = 0;
  auto alloc = [&](size_t bytes) {
    size_t o = off; off += (bytes + 255) & ~(size_t)255; return o;
  };
  // zero-init region first (single memset)
  size_t o_cnt = alloc((size_t)NREL * N_NODES * 4);
  size_t o_deg = alloc((size_t)(N_NODES + 1) * 4);
  size_t o_cur = alloc((size_t)N_NODES * 4);
  size_t o_h   = alloc((size_t)N_NODES * H1 * 4);
  size_t zero_bytes = off;
  size_t o_rp   = alloc((size_t)(N_NODES + 1) * 4);
  size_t o_esrc = alloc((size_t)E * 4);
  size_t o_erel = alloc((size_t)E * 4);
  size_t o_ew   = alloc((size_t)E * 4);
  size_t o_xh   = alloc((size_t)MPAD * KPAD * 2);
  size_t o_xl   = alloc((size_t)MPAD * KPAD * 2);
  size_t o_b1h  = alloc((size_t)NCOLS1 * KPAD * 2);
  size_t o_b1l  = alloc((size_t)NCOLS1 * KPAD * 2);
  size_t o_b2   = alloc((size_t)Y2C * H1 * 4);
  size_t o_y2   = alloc((size_t)N_NODES * Y2C * 4);
  size_t o_y1   = off;  // rest of ws: y1 chunk buffer (fp32)

  int*      cnt  = (int*)(ws + o_cnt);
  int*      deg  = (int*)(ws + o_deg);
  int*      cur  = (int*)(ws + o_cur);
  float*    h    = (float*)(ws + o_h);
  int*      rp   = (int*)(ws + o_rp);
  int*      esrc = (int*)(ws + o_esrc);
  int*      erel = (int*)(ws + o_erel);
  float*    ew   = (float*)(ws + o_ew);
  uint16_t* xh   = (uint16_t*)(ws + o_xh);
  uint16_t* xl   = (uint16_t*)(ws + o_xl);
  uint16_t* b1h  = (uint16_t*)(ws + o_b1h);
  uint16_t* b1l  = (uint16_t*)(ws + o_b1l);
  float*    b2t  = (float*)(ws + o_b2);
  float*    y2   = (float*)(ws + o_y2);
  float*    y1   = (float*)(ws + o_y1);

  // how many 256-col blocks of y1 fit in remaining ws (17 = single pass)
  size_t per_block = (size_t)MPAD * H1 * 4;
  int G = 1;
  if (ws_size > o_y1 + per_block) {
    size_t g = (ws_size - o_y1) / per_block;
    G = (int)(g > (size_t)NB1 ? (size_t)NB1 : g);
  }

  hipMemsetAsync(ws, 0, zero_bytes, stream);
  k_count<<<(E + 255) / 256, 256, 0, stream>>>(dst, et, deg, cnt, E);
  k_scan<<<1, 1024, 0, stream>>>(deg, rp);
  k_scatter<<<(E + 255) / 256, 256, 0, stream>>>(src, dst, et, rp, cur, cnt,
                                                 esrc, erel, ew, E);
  k_pack_x<<<(unsigned)(((long long)MPAD * KPAD + 255) / 256), 256, 0, stream>>>(x, xh, xl);
  k_pack_b1<<<(unsigned)(((long long)NCOLS1 * KPAD + 255) / 256), 256, 0, stream>>>(W1, root1, b1h, b1l);
  k_pack_b2<<<(Y2C * H1 + 255) / 256, 256, 0, stream>>>(W2, root2, b2t);

  for (int r0 = 0; r0 < NB1; r0 += G) {
    int nb = (NB1 - r0 < G) ? (NB1 - r0) : G;
    dim3 grid(MPAD / 128, nb * 2);
    k_gemm1<<<grid, 256, 0, stream>>>(xh, xl,
                                      b1h + (size_t)r0 * H1 * KPAD,
                                      b1l + (size_t)r0 * H1 * KPAD,
                                      y1, nb * H1);
    k_agg1<<<N_NODES, 256, 0, stream>>>(y1, esrc, erel, ew, rp, h, r0, nb, nb * H1);
  }
  k_fin1<<<(N_NODES * H1 + 255) / 256, 256, 0, stream>>>(h, b1);
  k_gemm2<<<(N_NODES * Y2C + 255) / 256, 256, 0, stream>>>(h, b2t, y2);
  k_agg2<<<(N_NODES + 3) / 4, 256, 0, stream>>>(y2, esrc, erel, ew, rp, b2,
                                                (float*)d_out);
  (void)n_in; (void)out_size;
}

// Round 3
// 1582.513 us; speedup vs baseline: 1.0149x; 1.0149x over previous
//
#include <hip/hip_runtime.h>
#include <cstdint>
#include <cstddef>

#define N_NODES 40000
#define DIN     386
#define H1      256
#define NREL    16
#define KPAD    416      // 13*32: zero-padded K for layer-1 GEMM
#define MPAD    40064    // 313*128: zero-padded M
#define NB1     17       // 16 relation blocks + 1 root block, 256 cols each
#define NCOLS1  (NB1 * KPAD)    // not used; see below
#define NCOL1   (NB1 * H1)      // 4352
#define Y2C     (2 * NREL + 2)  // 34
#define N2PAD   48              // Y2C padded to 3*16
#define LDB2    264             // 256 + 8 pad (2-way bank spread for b128 reads)

typedef __attribute__((ext_vector_type(8))) short s8v;
typedef __attribute__((ext_vector_type(4))) float f4v;

__device__ __forceinline__ float bf2f(uint16_t v) {
  return __uint_as_float(((uint32_t)v) << 16);
}
__device__ __forceinline__ uint16_t f2bf(float f) {  // RNE
  uint32_t u = __float_as_uint(f);
  u += 0x7FFF + ((u >> 16) & 1);
  return (uint16_t)(u >> 16);
}
__device__ __forceinline__ f4v mfma_bf16(s8v a, s8v b, f4v c) {
  asm("v_mfma_f32_16x16x32_bf16 %0, %1, %2, %0" : "+v"(c) : "v"(a), "v"(b));
  return c;
}
__device__ __forceinline__ void gload16(const uint16_t* g, uint16_t* lds) {
  __builtin_amdgcn_global_load_lds(
      (const __attribute__((address_space(1))) unsigned int*)g,
      (__attribute__((address_space(3))) unsigned int*)lds, 16, 0, 0);
}

// ---------- CSR build ----------
__global__ void k_count(const int* __restrict__ dst, const int* __restrict__ et,
                        int* __restrict__ deg, int* __restrict__ cnt, int E) {
  int e = blockIdx.x * 256 + threadIdx.x;
  if (e < E) {
    int d = dst[e], r = et[e];
    atomicAdd(&deg[d], 1);
    atomicAdd(&cnt[r * N_NODES + d], 1);
  }
}

// parallel scan: 40 blocks local scan -> 1-wave scan of block sums -> add offsets
__global__ void k_s1(const int* __restrict__ deg, int* __restrict__ rowptr,
                     int* __restrict__ bsum) {
  __shared__ int sd[1024];
  int t = threadIdx.x;
  int i = blockIdx.x * 1024 + t;
  int v = (i < N_NODES) ? deg[i] : 0;
  sd[t] = v;
  __syncthreads();
  for (int off = 1; off < 1024; off <<= 1) {
    int x = (t >= off) ? sd[t - off] : 0;
    __syncthreads();
    sd[t] += x;
    __syncthreads();
  }
  if (i < N_NODES) rowptr[i + 1] = sd[t];
  if (t == 1023) bsum[blockIdx.x] = sd[t];
}
__global__ void k_s2(const int* __restrict__ bsum, int* __restrict__ bscan,
                     int* __restrict__ rowptr, int nb) {
  int lane = threadIdx.x & 63;
  int own = (lane < nb) ? bsum[lane] : 0;
  int v = own;
  for (int off = 1; off < 64; off <<= 1) {
    int x = __shfl_up(v, off);
    if (lane >= off) v += x;
  }
  if (lane < nb) bscan[lane] = v - own;  // exclusive prefix
  if (lane == 0) rowptr[0] = 0;
}
__global__ void k_s3(const int* __restrict__ bscan, int* __restrict__ rowptr) {
  int i = blockIdx.x * 1024 + threadIdx.x;
  if (i < N_NODES && blockIdx.x > 0) rowptr[i + 1] += bscan[blockIdx.x];
}

__global__ void k_scatter(const int* __restrict__ src, const int* __restrict__ dst,
                          const int* __restrict__ et, const int* __restrict__ rowptr,
                          int* __restrict__ cursor, const int* __restrict__ cnt,
                          int* __restrict__ es_src, int* __restrict__ es_rel,
                          float* __restrict__ es_w, int E) {
  int e = blockIdx.x * 256 + threadIdx.x;
  if (e < E) {
    int d = dst[e], r = et[e], s = src[e];
    int pos = atomicAdd(&cursor[d], 1);
    int idx = rowptr[d] + pos;
    es_src[idx] = s;
    es_rel[idx] = r;
    es_w[idx] = 1.0f / (float)cnt[r * N_NODES + d];
  }
}

// ---------- packs: split each fp32 value into hi/lo bf16 ----------
__global__ void k_pack_x(const float* __restrict__ x, uint16_t* __restrict__ xh,
                         uint16_t* __restrict__ xl) {
  long long i = (long long)blockIdx.x * 256 + threadIdx.x;
  if (i >= (long long)MPAD * KPAD) return;
  int n = (int)(i / KPAD), k = (int)(i % KPAD);
  float v = (n < N_NODES && k < DIN) ? x[(long long)n * DIN + k] : 0.0f;
  uint16_t h = f2bf(v);
  xh[i] = h;
  xl[i] = f2bf(v - bf2f(h));
}

__global__ void k_pack_b1(const float* __restrict__ W1, const float* __restrict__ root1,
                          uint16_t* __restrict__ Bh, uint16_t* __restrict__ Bl) {
  long long i = (long long)blockIdx.x * 256 + threadIdx.x;
  if (i >= (long long)NCOL1 * KPAD) return;
  int c = (int)(i / KPAD), k = (int)(i % KPAD);
  float v = 0.0f;
  if (k < DIN) {
    if (c < NREL * H1) {
      int r = c >> 8, j = c & 255;
      v = W1[((long long)r * DIN + k) * H1 + j];
    } else {
      v = root1[(long long)k * H1 + (c - NREL * H1)];
    }
  }
  uint16_t h = f2bf(v);
  Bh[i] = h;
  Bl[i] = f2bf(v - bf2f(h));
}

__global__ void k_pack_b2(const float* __restrict__ W2, const float* __restrict__ root2,
                          uint16_t* __restrict__ b2h, uint16_t* __restrict__ b2l) {
  int i = blockIdx.x * 256 + threadIdx.x;
  if (i >= N2PAD * H1) return;
  int c = i >> 8, k = i & 255;
  float v = 0.0f;
  if (c < 2 * NREL) { int r = c >> 1, j = c & 1; v = W2[(r * H1 + k) * 2 + j]; }
  else if (c < Y2C) v = root2[k * 2 + (c - 2 * NREL)];
  uint16_t h = f2bf(v);
  b2h[i] = h;
  b2l[i] = f2bf(v - bf2f(h));
}

// ---------- layer-1 GEMM (split bf16): C[m,c] = sum_k A[m,k]*B[c,k], fp32 out ----------
__global__ __launch_bounds__(256) void k_gemm1(
    const uint16_t* __restrict__ Ah, const uint16_t* __restrict__ Al,
    const uint16_t* __restrict__ Bh, const uint16_t* __restrict__ Bl,
    float* __restrict__ C, int ldc) {
  __shared__ __align__(16) uint16_t sAh[128 * 32];
  __shared__ __align__(16) uint16_t sAl[128 * 32];
  __shared__ __align__(16) uint16_t sBh[128 * 32];
  __shared__ __align__(16) uint16_t sBl[128 * 32];
  int tid = threadIdx.x;
  int lane = tid & 63, w = tid >> 6;
  int wr = w >> 1, wc = w & 1;
  long long bm = (long long)blockIdx.x * 128;
  long long bn = (long long)blockIdx.y * 128;

  f4v zero = {0.f, 0.f, 0.f, 0.f};
  f4v acc[4][4];
#pragma unroll
  for (int i = 0; i < 4; ++i)
#pragma unroll
    for (int j = 0; j < 4; ++j) acc[i][j] = zero;

  int lrow = lane & 15, lk = (lane >> 4) * 8;
  int srow0 = w * 32 + (lane >> 2);
  int srow1 = srow0 + 16;
  int skel = (lane & 3) * 8;

  for (int kk = 0; kk < KPAD; kk += 32) {
    gload16(Ah + (bm + srow0) * KPAD + kk + skel, sAh + w * 1024);
    gload16(Ah + (bm + srow1) * KPAD + kk + skel, sAh + w * 1024 + 512);
    gload16(Al + (bm + srow0) * KPAD + kk + skel, sAl + w * 1024);
    gload16(Al + (bm + srow1) * KPAD + kk + skel, sAl + w * 1024 + 512);
    gload16(Bh + (bn + srow0) * KPAD + kk + skel, sBh + w * 1024);
    gload16(Bh + (bn + srow1) * KPAD + kk + skel, sBh + w * 1024 + 512);
    gload16(Bl + (bn + srow0) * KPAD + kk + skel, sBl + w * 1024);
    gload16(Bl + (bn + srow1) * KPAD + kk + skel, sBl + w * 1024 + 512);
    __syncthreads();

    s8v ah[4], al[4];
#pragma unroll
    for (int mi = 0; mi < 4; ++mi) {
      ah[mi] = *(const s8v*)(sAh + (wr * 64 + mi * 16 + lrow) * 32 + lk);
      al[mi] = *(const s8v*)(sAl + (wr * 64 + mi * 16 + lrow) * 32 + lk);
    }
#pragma unroll
    for (int ni = 0; ni < 4; ++ni) {
      s8v bh = *(const s8v*)(sBh + (wc * 64 + ni * 16 + lrow) * 32 + lk);
      s8v bl = *(const s8v*)(sBl + (wc * 64 + ni * 16 + lrow) * 32 + lk);
#pragma unroll
      for (int mi = 0; mi < 4; ++mi) {
        acc[mi][ni] = mfma_bf16(ah[mi], bh, acc[mi][ni]);
        acc[mi][ni] = mfma_bf16(al[mi], bh, acc[mi][ni]);
        acc[mi][ni] = mfma_bf16(ah[mi], bl, acc[mi][ni]);
      }
    }
    __syncthreads();
  }
  int rg = (lane >> 4) * 4;
#pragma unroll
  for (int mi = 0; mi < 4; ++mi) {
#pragma unroll
    for (int ni = 0; ni < 4; ++ni) {
      long long col = bn + wc * 64 + ni * 16 + (lane & 15);
#pragma unroll
      for (int r = 0; r < 4; ++r) {
        long long row = bm + wr * 64 + mi * 16 + rg + r;
        C[row * ldc + col] = acc[mi][ni][r];
      }
    }
  }
}

// ---------- aggregation 1 ----------
__global__ void k_agg1(const float* __restrict__ y1,
                       const int* __restrict__ es_src, const int* __restrict__ es_rel,
                       const float* __restrict__ es_w, const int* __restrict__ rowptr,
                       float* __restrict__ h, int r0, int nb, int ldy) {
  int n = blockIdx.x;
  int c = threadIdx.x;
  float acc = h[(long long)n * H1 + c];
  int e0 = rowptr[n], e1 = rowptr[n + 1];
  int rhi = r0 + nb;
  for (int e = e0; e < e1; ++e) {
    int r = es_rel[e];
    if (r >= r0 && r < rhi) {
      int s = es_src[e];
      float wgt = es_w[e];
      acc += wgt * y1[(long long)s * ldy + (r - r0) * H1 + c];
    }
  }
  if (r0 <= NREL && NREL < rhi)  // root block (index 16) in this chunk
    acc += y1[(long long)n * ldy + (NREL - r0) * H1 + c];
  h[(long long)n * H1 + c] = acc;
}

// ---------- fin1: bias+relu, emit h as bf16 hi/lo (zero-padded rows to MPAD) ----------
__global__ void k_fin1_pack(const float* __restrict__ h, const float* __restrict__ b1,
                            uint16_t* __restrict__ hh, uint16_t* __restrict__ hl) {
  long long i = (long long)blockIdx.x * 256 + threadIdx.x;
  if (i >= (long long)MPAD * H1) return;
  int n = (int)(i >> 8), c = (int)(i & 255);
  float v = 0.0f;
  if (n < N_NODES) {
    v = h[i] + b1[c];
    v = v > 0.f ? v : 0.f;
  }
  uint16_t hi = f2bf(v);
  hh[i] = hi;
  hl[i] = f2bf(v - bf2f(hi));
}

// ---------- layer-2 transform via MFMA: y2[M, 34] = h @ B2^T ----------
__global__ __launch_bounds__(256) void k_gemm2m(
    const uint16_t* __restrict__ hh, const uint16_t* __restrict__ hl,
    const uint16_t* __restrict__ b2h, const uint16_t* __restrict__ b2l,
    float* __restrict__ y2) {
  __shared__ __align__(16) uint16_t sB[2][N2PAD * LDB2];  // hi/lo, [48][264]
  __shared__ __align__(16) uint16_t sA[2][128 * 32];
  int tid = threadIdx.x, lane = tid & 63, w = tid >> 6;
  long long bm = (long long)blockIdx.x * 128;

  // load full B (48x256 x2) into LDS once, padded rows
  for (int cid = tid; cid < N2PAD * 32; cid += 256) {
    int row = cid >> 5, off = cid & 31;
    *(uint4*)(&sB[0][row * LDB2 + off * 8]) = *(const uint4*)(b2h + row * H1 + off * 8);
    *(uint4*)(&sB[1][row * LDB2 + off * 8]) = *(const uint4*)(b2l + row * H1 + off * 8);
  }

  f4v zero = {0.f, 0.f, 0.f, 0.f};
  f4v acc[2][3];
#pragma unroll
  for (int i = 0; i < 2; ++i)
#pragma unroll
    for (int j = 0; j < 3; ++j) acc[i][j] = zero;

  int lrow = lane & 15, lk = (lane >> 4) * 8;
  int srow0 = w * 32 + (lane >> 2), srow1 = srow0 + 16;
  int skel = (lane & 3) * 8;

  for (int kk = 0; kk < H1; kk += 32) {
    gload16(hh + (bm + srow0) * H1 + kk + skel, &sA[0][w * 1024]);
    gload16(hh + (bm + srow1) * H1 + kk + skel, &sA[0][w * 1024 + 512]);
    gload16(hl + (bm + srow0) * H1 + kk + skel, &sA[1][w * 1024]);
    gload16(hl + (bm + srow1) * H1 + kk + skel, &sA[1][w * 1024 + 512]);
    __syncthreads();

    s8v ah[2], al[2];
#pragma unroll
    for (int mi = 0; mi < 2; ++mi) {
      ah[mi] = *(const s8v*)(&sA[0][(w * 32 + mi * 16 + lrow) * 32 + lk]);
      al[mi] = *(const s8v*)(&sA[1][(w * 32 + mi * 16 + lrow) * 32 + lk]);
    }
#pragma unroll
    for (int nj = 0; nj < 3; ++nj) {
      s8v bh = *(const s8v*)(&sB[0][(nj * 16 + lrow) * LDB2 + kk + lk]);
      s8v bl = *(const s8v*)(&sB[1][(nj * 16 + lrow) * LDB2 + kk + lk]);
#pragma unroll
      for (int mi = 0; mi < 2; ++mi) {
        acc[mi][nj] = mfma_bf16(ah[mi], bh, acc[mi][nj]);
        acc[mi][nj] = mfma_bf16(al[mi], bh, acc[mi][nj]);
        acc[mi][nj] = mfma_bf16(ah[mi], bl, acc[mi][nj]);
      }
    }
    __syncthreads();
  }
  int rg = (lane >> 4) * 4;
#pragma unroll
  for (int mi = 0; mi < 2; ++mi) {
#pragma unroll
    for (int nj = 0; nj < 3; ++nj) {
      int col = nj * 16 + (lane & 15);
      if (col < Y2C) {
#pragma unroll
        for (int r = 0; r < 4; ++r) {
          long long row = bm + w * 32 + mi * 16 + rg + r;
          if (row < N_NODES) y2[row * Y2C + col] = acc[mi][nj][r];
        }
      }
    }
  }
}

// ---------- aggregation 2 + tanh ----------
__global__ void k_agg2(const float* __restrict__ y2, const int* __restrict__ es_src,
                       const int* __restrict__ es_rel, const float* __restrict__ es_w,
                       const int* __restrict__ rowptr, const float* __restrict__ b2,
                       float* __restrict__ out) {
  int n = blockIdx.x * 4 + (threadIdx.x >> 6);
  int lane = threadIdx.x & 63;
  if (n >= N_NODES) return;
  float a0 = 0.f, a1 = 0.f;
  int e0 = rowptr[n], e1 = rowptr[n + 1];
  for (int e = e0 + lane; e < e1; e += 64) {
    int s = es_src[e], r = es_rel[e];
    float wgt = es_w[e];
    a0 += wgt * y2[s * Y2C + r * 2];
    a1 += wgt * y2[s * Y2C + r * 2 + 1];
  }
#pragma unroll
  for (int off = 32; off > 0; off >>= 1) {
    a0 += __shfl_down(a0, off);
    a1 += __shfl_down(a1, off);
  }
  if (lane == 0) {
    a0 += y2[n * Y2C + 2 * NREL] + b2[0];
    a1 += y2[n * Y2C + 2 * NREL + 1] + b2[1];
    out[n * 2] = tanhf(a0);
    out[n * 2 + 1] = tanhf(a1);
  }
}

extern "C" void kernel_launch(void* const* d_in, const int* in_sizes, int n_in,
                              void* d_out, int out_size, void* d_ws, size_t ws_size,
                              hipStream_t stream) {
  const float* x     = (const float*)d_in[0];
  const int*   ei    = (const int*)d_in[1];
  const int*   et    = (const int*)d_in[2];
  const float* W1    = (const float*)d_in[3];
  const float* root1 = (const float*)d_in[4];
  const float* b1    = (const float*)d_in[5];
  const float* W2    = (const float*)d_in[6];
  const float* root2 = (const float*)d_in[7];
  const float* b2    = (const float*)d_in[8];
  const int E = in_sizes[2];
  const int* src = ei;
  const int* dst = ei + E;

  char* ws = (char*)d_ws;
  size_t off = 0;
  auto alloc = [&](size_t bytes) {
    size_t o = off; off += (bytes + 255) & ~(size_t)255; return o;
  };
  // zero-init region first (single memset)
  size_t o_cnt = alloc((size_t)NREL * N_NODES * 4);
  size_t o_deg = alloc((size_t)(N_NODES + 1) * 4);
  size_t o_cur = alloc((size_t)N_NODES * 4);
  size_t o_h   = alloc((size_t)N_NODES * H1 * 4);
  size_t zero_bytes = off;
  size_t o_rp   = alloc((size_t)(N_NODES + 1) * 4);
  size_t o_bsum = alloc(64 * 4);
  size_t o_bscn = alloc(64 * 4);
  size_t o_esrc = alloc((size_t)E * 4);
  size_t o_erel = alloc((size_t)E * 4);
  size_t o_ew   = alloc((size_t)E * 4);
  size_t o_xh   = alloc((size_t)MPAD * KPAD * 2);
  size_t o_xl   = alloc((size_t)MPAD * KPAD * 2);
  size_t o_b1h  = alloc((size_t)NCOL1 * KPAD * 2);
  size_t o_b1l  = alloc((size_t)NCOL1 * KPAD * 2);
  size_t o_b2h  = alloc((size_t)N2PAD * H1 * 2);
  size_t o_b2l  = alloc((size_t)N2PAD * H1 * 2);
  size_t o_hh   = alloc((size_t)MPAD * H1 * 2);
  size_t o_hl   = alloc((size_t)MPAD * H1 * 2);
  size_t o_y2   = alloc((size_t)N_NODES * Y2C * 4);
  size_t o_y1   = off;  // rest of ws: y1 chunk buffer (fp32)

  int*      cnt  = (int*)(ws + o_cnt);
  int*      deg  = (int*)(ws + o_deg);
  int*      cur  = (int*)(ws + o_cur);
  float*    h    = (float*)(ws + o_h);
  int*      rp   = (int*)(ws + o_rp);
  int*      bsum = (int*)(ws + o_bsum);
  int*      bscn = (int*)(ws + o_bscn);
  int*      esrc = (int*)(ws + o_esrc);
  int*      erel = (int*)(ws + o_erel);
  float*    ew   = (float*)(ws + o_ew);
  uint16_t* xh   = (uint16_t*)(ws + o_xh);
  uint16_t* xl   = (uint16_t*)(ws + o_xl);
  uint16_t* b1h  = (uint16_t*)(ws + o_b1h);
  uint16_t* b1l  = (uint16_t*)(ws + o_b1l);
  uint16_t* b2h  = (uint16_t*)(ws + o_b2h);
  uint16_t* b2l  = (uint16_t*)(ws + o_b2l);
  uint16_t* hh   = (uint16_t*)(ws + o_hh);
  uint16_t* hl   = (uint16_t*)(ws + o_hl);
  float*    y2   = (float*)(ws + o_y2);
  float*    y1   = (float*)(ws + o_y1);

  size_t per_block = (size_t)MPAD * H1 * 4;
  int G = 1;
  if (ws_size > o_y1 + per_block) {
    size_t g = (ws_size - o_y1) / per_block;
    G = (int)(g > (size_t)NB1 ? (size_t)NB1 : g);
  }

  const int NSB = (N_NODES + 1023) / 1024;  // 40 scan blocks

  hipMemsetAsync(ws, 0, zero_bytes, stream);
  k_count<<<(E + 255) / 256, 256, 0, stream>>>(dst, et, deg, cnt, E);
  k_s1<<<NSB, 1024, 0, stream>>>(deg, rp, bsum);
  k_s2<<<1, 64, 0, stream>>>(bsum, bscn, rp, NSB);
  k_s3<<<NSB, 1024, 0, stream>>>(bscn, rp);
  k_scatter<<<(E + 255) / 256, 256, 0, stream>>>(src, dst, et, rp, cur, cnt,
                                                 esrc, erel, ew, E);
  k_pack_x<<<(unsigned)(((long long)MPAD * KPAD + 255) / 256), 256, 0, stream>>>(x, xh, xl);
  k_pack_b1<<<(unsigned)(((long long)NCOL1 * KPAD + 255) / 256), 256, 0, stream>>>(W1, root1, b1h, b1l);
  k_pack_b2<<<(N2PAD * H1 + 255) / 256, 256, 0, stream>>>(W2, root2, b2h, b2l);

  for (int r0 = 0; r0 < NB1; r0 += G) {
    int nb = (NB1 - r0 < G) ? (NB1 - r0) : G;
    dim3 grid(MPAD / 128, nb * 2);
    k_gemm1<<<grid, 256, 0, stream>>>(xh, xl,
                                      b1h + (size_t)r0 * H1 * KPAD,
                                      b1l + (size_t)r0 * H1 * KPAD,
                                      y1, nb * H1);
    k_agg1<<<N_NODES, 256, 0, stream>>>(y1, esrc, erel, ew, rp, h, r0, nb, nb * H1);
  }
  k_fin1_pack<<<(unsigned)(((long long)MPAD * H1 + 255) / 256), 256, 0, stream>>>(h, b1, hh, hl);
  k_gemm2m<<<MPAD / 128, 256, 0, stream>>>(hh, hl, b2h, b2l, y2);
  k_agg2<<<(N_NODES + 3) / 4, 256, 0, stream>>>(y2, esrc, erel, ew, rp, b2,
                                                (float*)d_out);
  (void)n_in; (void)out_size;
}

// Round 4
// 849.956 us; speedup vs baseline: 1.8896x; 1.8619x over previous
//
#include <hip/hip_runtime.h>
#include <cstdint>
#include <cstddef>

#define N_NODES 40000
#define DIN     386
#define H1      256
#define NREL    16
#define KPAD    416      // 13*32: zero-padded K for layer-1 GEMM
#define MPAD    40064    // 313*128: zero-padded M
#define NB1     17       // 16 relation blocks + 1 root block, 256 cols each
#define NCOL1   (NB1 * H1)      // 4352
#define Y2C     (2 * NREL + 2)  // 34
#define N2PAD   48              // Y2C padded to 3*16
#define LDB2    264             // 256 + 8 pad

typedef __attribute__((ext_vector_type(8))) short s8v;
typedef __attribute__((ext_vector_type(4))) float f4v;

__device__ __forceinline__ float bf2f(uint16_t v) {
  return __uint_as_float(((uint32_t)v) << 16);
}
__device__ __forceinline__ uint16_t f2bf(float f) {  // RNE
  uint32_t u = __float_as_uint(f);
  u += 0x7FFF + ((u >> 16) & 1);
  return (uint16_t)(u >> 16);
}
__device__ __forceinline__ uint16_t f2h(float f) {   // fp16 RNE via native cast
  _Float16 h = (_Float16)f;
  return *(uint16_t*)&h;
}
__device__ __forceinline__ float h2f(uint16_t u) {
  _Float16 h = *(_Float16*)&u;
  return (float)h;
}
__device__ __forceinline__ f4v mfma_bf16(s8v a, s8v b, f4v c) {
  asm("v_mfma_f32_16x16x32_bf16 %0, %1, %2, %0" : "+v"(c) : "v"(a), "v"(b));
  return c;
}
__device__ __forceinline__ void gload16(const uint16_t* g, uint16_t* lds) {
  __builtin_amdgcn_global_load_lds(
      (const __attribute__((address_space(1))) unsigned int*)g,
      (__attribute__((address_space(3))) unsigned int*)lds, 16, 0, 0);
}

// ---------- CSR build ----------
__global__ void k_count(const int* __restrict__ dst, const int* __restrict__ et,
                        int* __restrict__ deg, int* __restrict__ cnt, int E) {
  int e = blockIdx.x * 256 + threadIdx.x;
  if (e < E) {
    int d = dst[e], r = et[e];
    atomicAdd(&deg[d], 1);
    atomicAdd(&cnt[r * N_NODES + d], 1);
  }
}

__global__ void k_s1(const int* __restrict__ deg, int* __restrict__ rowptr,
                     int* __restrict__ bsum) {
  __shared__ int sd[1024];
  int t = threadIdx.x;
  int i = blockIdx.x * 1024 + t;
  int v = (i < N_NODES) ? deg[i] : 0;
  sd[t] = v;
  __syncthreads();
  for (int off = 1; off < 1024; off <<= 1) {
    int x = (t >= off) ? sd[t - off] : 0;
    __syncthreads();
    sd[t] += x;
    __syncthreads();
  }
  if (i < N_NODES) rowptr[i + 1] = sd[t];
  if (t == 1023) bsum[blockIdx.x] = sd[t];
}
__global__ void k_s2(const int* __restrict__ bsum, int* __restrict__ bscan,
                     int* __restrict__ rowptr, int nb) {
  int lane = threadIdx.x & 63;
  int own = (lane < nb) ? bsum[lane] : 0;
  int v = own;
  for (int off = 1; off < 64; off <<= 1) {
    int x = __shfl_up(v, off);
    if (lane >= off) v += x;
  }
  if (lane < nb) bscan[lane] = v - own;  // exclusive prefix
  if (lane == 0) rowptr[0] = 0;
}
__global__ void k_s3(const int* __restrict__ bscan, int* __restrict__ rowptr) {
  int i = blockIdx.x * 1024 + threadIdx.x;
  if (i < N_NODES && blockIdx.x > 0) rowptr[i + 1] += bscan[blockIdx.x];
}

__global__ void k_scatter(const int* __restrict__ src, const int* __restrict__ dst,
                          const int* __restrict__ et, const int* __restrict__ rowptr,
                          int* __restrict__ cursor, const int* __restrict__ cnt,
                          int* __restrict__ es_src, int* __restrict__ es_rel,
                          float* __restrict__ es_w, int E) {
  int e = blockIdx.x * 256 + threadIdx.x;
  if (e < E) {
    int d = dst[e], r = et[e], s = src[e];
    int pos = atomicAdd(&cursor[d], 1);
    int idx = rowptr[d] + pos;
    es_src[idx] = s;
    es_rel[idx] = r;
    es_w[idx] = 1.0f / (float)cnt[r * N_NODES + d];
  }
}

// ---------- packs: split fp32 into hi/lo bf16 ----------
__global__ void k_pack_x(const float* __restrict__ x, uint16_t* __restrict__ xh,
                         uint16_t* __restrict__ xl) {
  long long i = (long long)blockIdx.x * 256 + threadIdx.x;
  if (i >= (long long)MPAD * KPAD) return;
  int n = (int)(i / KPAD), k = (int)(i % KPAD);
  float v = (n < N_NODES && k < DIN) ? x[(long long)n * DIN + k] : 0.0f;
  uint16_t h = f2bf(v);
  xh[i] = h;
  xl[i] = f2bf(v - bf2f(h));
}

__global__ void k_pack_b1(const float* __restrict__ W1, const float* __restrict__ root1,
                          uint16_t* __restrict__ Bh, uint16_t* __restrict__ Bl) {
  long long i = (long long)blockIdx.x * 256 + threadIdx.x;
  if (i >= (long long)NCOL1 * KPAD) return;
  int c = (int)(i / KPAD), k = (int)(i % KPAD);
  float v = 0.0f;
  if (k < DIN) {
    if (c < NREL * H1) {
      int r = c >> 8, j = c & 255;
      v = W1[((long long)r * DIN + k) * H1 + j];
    } else {
      v = root1[(long long)k * H1 + (c - NREL * H1)];
    }
  }
  uint16_t h = f2bf(v);
  Bh[i] = h;
  Bl[i] = f2bf(v - bf2f(h));
}

__global__ void k_pack_b2(const float* __restrict__ W2, const float* __restrict__ root2,
                          uint16_t* __restrict__ b2h, uint16_t* __restrict__ b2l) {
  int i = blockIdx.x * 256 + threadIdx.x;
  if (i >= N2PAD * H1) return;
  int c = i >> 8, k = i & 255;
  float v = 0.0f;
  if (c < 2 * NREL) { int r = c >> 1, j = c & 1; v = W2[(r * H1 + k) * 2 + j]; }
  else if (c < Y2C) v = root2[k * 2 + (c - 2 * NREL)];
  uint16_t h = f2bf(v);
  b2h[i] = h;
  b2l[i] = f2bf(v - bf2f(h));
}

// ---------- layer-1 GEMM (split bf16), fp16 out ----------
__global__ __launch_bounds__(256) void k_gemm1(
    const uint16_t* __restrict__ Ah, const uint16_t* __restrict__ Al,
    const uint16_t* __restrict__ Bh, const uint16_t* __restrict__ Bl,
    uint16_t* __restrict__ C, int ldc) {
  __shared__ __align__(16) uint16_t sAh[128 * 32];
  __shared__ __align__(16) uint16_t sAl[128 * 32];
  __shared__ __align__(16) uint16_t sBh[128 * 32];
  __shared__ __align__(16) uint16_t sBl[128 * 32];
  int tid = threadIdx.x;
  int lane = tid & 63, w = tid >> 6;
  int wr = w >> 1, wc = w & 1;
  long long bm = (long long)blockIdx.x * 128;
  long long bn = (long long)blockIdx.y * 128;

  f4v zero = {0.f, 0.f, 0.f, 0.f};
  f4v acc[4][4];
#pragma unroll
  for (int i = 0; i < 4; ++i)
#pragma unroll
    for (int j = 0; j < 4; ++j) acc[i][j] = zero;

  int lrow = lane & 15, lk = (lane >> 4) * 8;
  int srow0 = w * 32 + (lane >> 2);
  int srow1 = srow0 + 16;
  int skel = (lane & 3) * 8;

  for (int kk = 0; kk < KPAD; kk += 32) {
    gload16(Ah + (bm + srow0) * KPAD + kk + skel, sAh + w * 1024);
    gload16(Ah + (bm + srow1) * KPAD + kk + skel, sAh + w * 1024 + 512);
    gload16(Al + (bm + srow0) * KPAD + kk + skel, sAl + w * 1024);
    gload16(Al + (bm + srow1) * KPAD + kk + skel, sAl + w * 1024 + 512);
    gload16(Bh + (bn + srow0) * KPAD + kk + skel, sBh + w * 1024);
    gload16(Bh + (bn + srow1) * KPAD + kk + skel, sBh + w * 1024 + 512);
    gload16(Bl + (bn + srow0) * KPAD + kk + skel, sBl + w * 1024);
    gload16(Bl + (bn + srow1) * KPAD + kk + skel, sBl + w * 1024 + 512);
    __syncthreads();

    s8v ah[4], al[4];
#pragma unroll
    for (int mi = 0; mi < 4; ++mi) {
      ah[mi] = *(const s8v*)(sAh + (wr * 64 + mi * 16 + lrow) * 32 + lk);
      al[mi] = *(const s8v*)(sAl + (wr * 64 + mi * 16 + lrow) * 32 + lk);
    }
#pragma unroll
    for (int ni = 0; ni < 4; ++ni) {
      s8v bh = *(const s8v*)(sBh + (wc * 64 + ni * 16 + lrow) * 32 + lk);
      s8v bl = *(const s8v*)(sBl + (wc * 64 + ni * 16 + lrow) * 32 + lk);
#pragma unroll
      for (int mi = 0; mi < 4; ++mi) {
        acc[mi][ni] = mfma_bf16(ah[mi], bh, acc[mi][ni]);
        acc[mi][ni] = mfma_bf16(al[mi], bh, acc[mi][ni]);
        acc[mi][ni] = mfma_bf16(ah[mi], bl, acc[mi][ni]);
      }
    }
    __syncthreads();
  }
  int rg = (lane >> 4) * 4;
#pragma unroll
  for (int mi = 0; mi < 4; ++mi) {
#pragma unroll
    for (int ni = 0; ni < 4; ++ni) {
      long long col = bn + wc * 64 + ni * 16 + (lane & 15);
#pragma unroll
      for (int r = 0; r < 4; ++r) {
        long long row = bm + wr * 64 + mi * 16 + rg + r;
        C[row * ldc + col] = f2h(acc[mi][ni][r]);
      }
    }
  }
}

// ---------- aggregation 1: wave-per-node, metadata prefetch + shfl broadcast ----------
__global__ __launch_bounds__(256) void k_agg1(
    const uint16_t* __restrict__ y1,   // fp16 chunk [MPAD][ldy]
    const int* __restrict__ es_src, const int* __restrict__ es_rel,
    const float* __restrict__ es_w, const int* __restrict__ rowptr,
    float* __restrict__ h, int r0, int nb, int ldy) {
  int n = blockIdx.x * 4 + (threadIdx.x >> 6);
  int lane = threadIdx.x & 63;
  if (n >= N_NODES) return;
  int e0 = rowptr[n], e1 = rowptr[n + 1];
  int deg = e1 - e0;
  float4 acc = {0.f, 0.f, 0.f, 0.f};

  // prefetch up to 64 edges' metadata in one parallel round
  int mrel = -1000, msrc = 0;
  float mw = 0.f;
  if (lane < deg) {
    int e = e0 + lane;
    mrel = es_rel[e] - r0;
    msrc = es_src[e];
    mw = es_w[e];
  }
  int dcap = deg <= 64 ? deg : 64;
  for (int j = 0; j < dcap; ++j) {
    int off = __shfl(mrel, j);
    if ((unsigned)off < (unsigned)nb) {
      int s = __shfl(msrc, j);
      float wgt = __shfl(mw, j);
      uint2 v = *(const uint2*)(y1 + (long long)s * ldy + off * H1 + lane * 4);
      acc.x += wgt * h2f((uint16_t)v.x);
      acc.y += wgt * h2f((uint16_t)(v.x >> 16));
      acc.z += wgt * h2f((uint16_t)v.y);
      acc.w += wgt * h2f((uint16_t)(v.y >> 16));
    }
  }
  // rare tail (deg > 64): direct per-edge path
  for (int e = e0 + 64; e < e1; ++e) {
    int off = es_rel[e] - r0;
    if ((unsigned)off < (unsigned)nb) {
      int s = es_src[e];
      float wgt = es_w[e];
      uint2 v = *(const uint2*)(y1 + (long long)s * ldy + off * H1 + lane * 4);
      acc.x += wgt * h2f((uint16_t)v.x);
      acc.y += wgt * h2f((uint16_t)(v.x >> 16));
      acc.z += wgt * h2f((uint16_t)v.y);
      acc.w += wgt * h2f((uint16_t)(v.y >> 16));
    }
  }
  // root block (relation index NREL) if in this chunk, weight 1, own row
  if (r0 <= NREL && NREL < r0 + nb) {
    uint2 v = *(const uint2*)(y1 + (long long)n * ldy + (NREL - r0) * H1 + lane * 4);
    acc.x += h2f((uint16_t)v.x);
    acc.y += h2f((uint16_t)(v.x >> 16));
    acc.z += h2f((uint16_t)v.y);
    acc.w += h2f((uint16_t)(v.y >> 16));
  }
  float* hp = h + (long long)n * H1 + lane * 4;
  float4 old = *(const float4*)hp;
  old.x += acc.x; old.y += acc.y; old.z += acc.z; old.w += acc.w;
  *(float4*)hp = old;
}

// ---------- fin1: bias+relu, emit h as bf16 hi/lo (rows padded to MPAD) ----------
__global__ void k_fin1_pack(const float* __restrict__ h, const float* __restrict__ b1,
                            uint16_t* __restrict__ hh, uint16_t* __restrict__ hl) {
  long long i = (long long)blockIdx.x * 256 + threadIdx.x;
  if (i >= (long long)MPAD * H1) return;
  int n = (int)(i >> 8), c = (int)(i & 255);
  float v = 0.0f;
  if (n < N_NODES) {
    v = h[i] + b1[c];
    v = v > 0.f ? v : 0.f;
  }
  uint16_t hi = f2bf(v);
  hh[i] = hi;
  hl[i] = f2bf(v - bf2f(hi));
}

// ---------- layer-2 transform via MFMA: y2[M, 34] = h @ B2^T ----------
__global__ __launch_bounds__(256) void k_gemm2m(
    const uint16_t* __restrict__ hh, const uint16_t* __restrict__ hl,
    const uint16_t* __restrict__ b2h, const uint16_t* __restrict__ b2l,
    float* __restrict__ y2) {
  __shared__ __align__(16) uint16_t sB[2][N2PAD * LDB2];
  __shared__ __align__(16) uint16_t sA[2][128 * 32];
  int tid = threadIdx.x, lane = tid & 63, w = tid >> 6;
  long long bm = (long long)blockIdx.x * 128;

  for (int cid = tid; cid < N2PAD * 32; cid += 256) {
    int row = cid >> 5, off = cid & 31;
    *(uint4*)(&sB[0][row * LDB2 + off * 8]) = *(const uint4*)(b2h + row * H1 + off * 8);
    *(uint4*)(&sB[1][row * LDB2 + off * 8]) = *(const uint4*)(b2l + row * H1 + off * 8);
  }

  f4v zero = {0.f, 0.f, 0.f, 0.f};
  f4v acc[2][3];
#pragma unroll
  for (int i = 0; i < 2; ++i)
#pragma unroll
    for (int j = 0; j < 3; ++j) acc[i][j] = zero;

  int lrow = lane & 15, lk = (lane >> 4) * 8;
  int srow0 = w * 32 + (lane >> 2), srow1 = srow0 + 16;
  int skel = (lane & 3) * 8;

  for (int kk = 0; kk < H1; kk += 32) {
    gload16(hh + (bm + srow0) * H1 + kk + skel, &sA[0][w * 1024]);
    gload16(hh + (bm + srow1) * H1 + kk + skel, &sA[0][w * 1024 + 512]);
    gload16(hl + (bm + srow0) * H1 + kk + skel, &sA[1][w * 1024]);
    gload16(hl + (bm + srow1) * H1 + kk + skel, &sA[1][w * 1024 + 512]);
    __syncthreads();

    s8v ah[2], al[2];
#pragma unroll
    for (int mi = 0; mi < 2; ++mi) {
      ah[mi] = *(const s8v*)(&sA[0][(w * 32 + mi * 16 + lrow) * 32 + lk]);
      al[mi] = *(const s8v*)(&sA[1][(w * 32 + mi * 16 + lrow) * 32 + lk]);
    }
#pragma unroll
    for (int nj = 0; nj < 3; ++nj) {
      s8v bh = *(const s8v*)(&sB[0][(nj * 16 + lrow) * LDB2 + kk + lk]);
      s8v bl = *(const s8v*)(&sB[1][(nj * 16 + lrow) * LDB2 + kk + lk]);
#pragma unroll
      for (int mi = 0; mi < 2; ++mi) {
        acc[mi][nj] = mfma_bf16(ah[mi], bh, acc[mi][nj]);
        acc[mi][nj] = mfma_bf16(al[mi], bh, acc[mi][nj]);
        acc[mi][nj] = mfma_bf16(ah[mi], bl, acc[mi][nj]);
      }
    }
    __syncthreads();
  }
  int rg = (lane >> 4) * 4;
#pragma unroll
  for (int mi = 0; mi < 2; ++mi) {
#pragma unroll
    for (int nj = 0; nj < 3; ++nj) {
      int col = nj * 16 + (lane & 15);
      if (col < Y2C) {
#pragma unroll
        for (int r = 0; r < 4; ++r) {
          long long row = bm + w * 32 + mi * 16 + rg + r;
          if (row < N_NODES) y2[row * Y2C + col] = acc[mi][nj][r];
        }
      }
    }
  }
}

// ---------- aggregation 2 + tanh ----------
__global__ void k_agg2(const float* __restrict__ y2, const int* __restrict__ es_src,
                       const int* __restrict__ es_rel, const float* __restrict__ es_w,
                       const int* __restrict__ rowptr, const float* __restrict__ b2,
                       float* __restrict__ out) {
  int n = blockIdx.x * 4 + (threadIdx.x >> 6);
  int lane = threadIdx.x & 63;
  if (n >= N_NODES) return;
  float a0 = 0.f, a1 = 0.f;
  int e0 = rowptr[n], e1 = rowptr[n + 1];
  for (int e = e0 + lane; e < e1; e += 64) {
    int s = es_src[e], r = es_rel[e];
    float wgt = es_w[e];
    a0 += wgt * y2[s * Y2C + r * 2];
    a1 += wgt * y2[s * Y2C + r * 2 + 1];
  }
#pragma unroll
  for (int off = 32; off > 0; off >>= 1) {
    a0 += __shfl_down(a0, off);
    a1 += __shfl_down(a1, off);
  }
  if (lane == 0) {
    a0 += y2[n * Y2C + 2 * NREL] + b2[0];
    a1 += y2[n * Y2C + 2 * NREL + 1] + b2[1];
    out[n * 2] = tanhf(a0);
    out[n * 2 + 1] = tanhf(a1);
  }
}

extern "C" void kernel_launch(void* const* d_in, const int* in_sizes, int n_in,
                              void* d_out, int out_size, void* d_ws, size_t ws_size,
                              hipStream_t stream) {
  const float* x     = (const float*)d_in[0];
  const int*   ei    = (const int*)d_in[1];
  const int*   et    = (const int*)d_in[2];
  const float* W1    = (const float*)d_in[3];
  const float* root1 = (const float*)d_in[4];
  const float* b1    = (const float*)d_in[5];
  const float* W2    = (const float*)d_in[6];
  const float* root2 = (const float*)d_in[7];
  const float* b2    = (const float*)d_in[8];
  const int E = in_sizes[2];
  const int* src = ei;
  const int* dst = ei + E;

  char* ws = (char*)d_ws;
  size_t off = 0;
  auto alloc = [&](size_t bytes) {
    size_t o = off; off += (bytes + 255) & ~(size_t)255; return o;
  };
  size_t o_cnt = alloc((size_t)NREL * N_NODES * 4);
  size_t o_deg = alloc((size_t)(N_NODES + 1) * 4);
  size_t o_cur = alloc((size_t)N_NODES * 4);
  size_t o_h   = alloc((size_t)N_NODES * H1 * 4);
  size_t zero_bytes = off;
  size_t o_rp   = alloc((size_t)(N_NODES + 1) * 4);
  size_t o_bsum = alloc(64 * 4);
  size_t o_bscn = alloc(64 * 4);
  size_t o_esrc = alloc((size_t)E * 4);
  size_t o_erel = alloc((size_t)E * 4);
  size_t o_ew   = alloc((size_t)E * 4);
  size_t o_xh   = alloc((size_t)MPAD * KPAD * 2);   // hh aliases this later
  size_t o_xl   = alloc((size_t)MPAD * KPAD * 2);   // hl aliases this later
  size_t o_b1h  = alloc((size_t)NCOL1 * KPAD * 2);
  size_t o_b1l  = alloc((size_t)NCOL1 * KPAD * 2);
  size_t o_b2h  = alloc((size_t)N2PAD * H1 * 2);
  size_t o_b2l  = alloc((size_t)N2PAD * H1 * 2);
  size_t o_y2   = alloc((size_t)N_NODES * Y2C * 4);
  size_t o_y1   = off;  // rest of ws: y1 chunk buffer (fp16)

  int*      cnt  = (int*)(ws + o_cnt);
  int*      deg  = (int*)(ws + o_deg);
  int*      cur  = (int*)(ws + o_cur);
  float*    h    = (float*)(ws + o_h);
  int*      rp   = (int*)(ws + o_rp);
  int*      bsum = (int*)(ws + o_bsum);
  int*      bscn = (int*)(ws + o_bscn);
  int*      esrc = (int*)(ws + o_esrc);
  int*      erel = (int*)(ws + o_erel);
  float*    ew   = (float*)(ws + o_ew);
  uint16_t* xh   = (uint16_t*)(ws + o_xh);
  uint16_t* xl   = (uint16_t*)(ws + o_xl);
  uint16_t* b1h  = (uint16_t*)(ws + o_b1h);
  uint16_t* b1l  = (uint16_t*)(ws + o_b1l);
  uint16_t* b2h  = (uint16_t*)(ws + o_b2h);
  uint16_t* b2l  = (uint16_t*)(ws + o_b2l);
  // hh/hl alias xh/xl: xh/xl are dead after the last k_gemm1; fin1_pack writes
  // hh/hl strictly later in stream order. (xh region 33.3MB >= hh 20.5MB.)
  uint16_t* hh   = (uint16_t*)(ws + o_xh);
  uint16_t* hl   = (uint16_t*)(ws + o_xl);
  float*    y2   = (float*)(ws + o_y2);
  uint16_t* y1   = (uint16_t*)(ws + o_y1);

  size_t per_block = (size_t)MPAD * H1 * 2;  // fp16 y1, one 256-col block
  int G = 1;
  if (ws_size > o_y1 + per_block) {
    size_t g = (ws_size - o_y1) / per_block;
    G = (int)(g > (size_t)NB1 ? (size_t)NB1 : g);
  }

  const int NSB = (N_NODES + 1023) / 1024;

  hipMemsetAsync(ws, 0, zero_bytes, stream);
  k_count<<<(E + 255) / 256, 256, 0, stream>>>(dst, et, deg, cnt, E);
  k_s1<<<NSB, 1024, 0, stream>>>(deg, rp, bsum);
  k_s2<<<1, 64, 0, stream>>>(bsum, bscn, rp, NSB);
  k_s3<<<NSB, 1024, 0, stream>>>(bscn, rp);
  k_scatter<<<(E + 255) / 256, 256, 0, stream>>>(src, dst, et, rp, cur, cnt,
                                                 esrc, erel, ew, E);
  k_pack_x<<<(unsigned)(((long long)MPAD * KPAD + 255) / 256), 256, 0, stream>>>(x, xh, xl);
  k_pack_b1<<<(unsigned)(((long long)NCOL1 * KPAD + 255) / 256), 256, 0, stream>>>(W1, root1, b1h, b1l);
  k_pack_b2<<<(N2PAD * H1 + 255) / 256, 256, 0, stream>>>(W2, root2, b2h, b2l);

  for (int r0 = 0; r0 < NB1; r0 += G) {
    int nb = (NB1 - r0 < G) ? (NB1 - r0) : G;
    dim3 grid(MPAD / 128, nb * 2);
    k_gemm1<<<grid, 256, 0, stream>>>(xh, xl,
                                      b1h + (size_t)r0 * H1 * KPAD,
                                      b1l + (size_t)r0 * H1 * KPAD,
                                      y1, nb * H1);
    k_agg1<<<(N_NODES + 3) / 4, 256, 0, stream>>>(y1, esrc, erel, ew, rp, h,
                                                  r0, nb, nb * H1);
  }
  k_fin1_pack<<<(unsigned)(((long long)MPAD * H1 + 255) / 256), 256, 0, stream>>>(h, b1, hh, hl);
  k_gemm2m<<<MPAD / 128, 256, 0, stream>>>(hh, hl, b2h, b2l, y2);
  k_agg2<<<(N_NODES + 3) / 4, 256, 0, stream>>>(y2, esrc, erel, ew, rp, b2,
                                                (float*)d_out);
  (void)n_in; (void)out_size;
}

// Round 5
// 540.456 us; speedup vs baseline: 2.9718x; 1.5727x over previous
//
#include <hip/hip_runtime.h>
#include <cstdint>
#include <cstddef>

#define N_NODES 40000
#define DIN     386
#define H1      256
#define NREL    16
#define KPAD    416      // 13*32: zero-padded K for layer-1 GEMM
#define MPAD    40064    // 313*128: zero-padded M
#define NB1     17       // 16 relation blocks + 1 root block, 256 cols each
#define NCOL1   (NB1 * H1)      // 4352
#define Y2C     (2 * NREL + 2)  // 34
#define N2PAD   48              // Y2C padded to 3*16
#define LDB2    264             // 256 + 8 pad (2-way bank spread)

typedef __attribute__((ext_vector_type(8))) short s8v;
typedef __attribute__((ext_vector_type(4))) float f4v;

__device__ __forceinline__ float bf2f(uint16_t v) {
  return __uint_as_float(((uint32_t)v) << 16);
}
__device__ __forceinline__ uint16_t f2bf(float f) {
  uint32_t u = __float_as_uint(f);
  u += 0x7FFF + ((u >> 16) & 1);
  return (uint16_t)(u >> 16);
}
__device__ __forceinline__ uint16_t f2h(float f) {
  _Float16 h = (_Float16)f;
  return *(uint16_t*)&h;
}
__device__ __forceinline__ float h2f(uint16_t u) {
  _Float16 h = *(_Float16*)&u;
  return (float)h;
}
__device__ __forceinline__ f4v mfma_f16(s8v a, s8v b, f4v c) {
  asm("v_mfma_f32_16x16x32_f16 %0, %1, %2, %0" : "+v"(c) : "v"(a), "v"(b));
  return c;
}
__device__ __forceinline__ void gload16(const uint16_t* g, uint16_t* lds) {
  __builtin_amdgcn_global_load_lds(
      (const __attribute__((address_space(1))) unsigned int*)g,
      (__attribute__((address_space(3))) unsigned int*)lds, 16, 0, 0);
}

// ---------- CSR build ----------
__global__ void k_count(const int* __restrict__ dst, const int* __restrict__ et,
                        int* __restrict__ deg, int* __restrict__ cnt, int E) {
  int e = blockIdx.x * 256 + threadIdx.x;
  if (e < E) {
    int d = dst[e], r = et[e];
    atomicAdd(&deg[d], 1);
    atomicAdd(&cnt[r * N_NODES + d], 1);
  }
}

__global__ void k_s1(const int* __restrict__ deg, int* __restrict__ rowptr,
                     int* __restrict__ bsum) {
  __shared__ int sd[1024];
  int t = threadIdx.x;
  int i = blockIdx.x * 1024 + t;
  int v = (i < N_NODES) ? deg[i] : 0;
  sd[t] = v;
  __syncthreads();
  for (int off = 1; off < 1024; off <<= 1) {
    int x = (t >= off) ? sd[t - off] : 0;
    __syncthreads();
    sd[t] += x;
    __syncthreads();
  }
  if (i < N_NODES) rowptr[i + 1] = sd[t];
  if (t == 1023) bsum[blockIdx.x] = sd[t];
}
__global__ void k_s2(const int* __restrict__ bsum, int* __restrict__ bscan,
                     int* __restrict__ rowptr, int nb) {
  int lane = threadIdx.x & 63;
  int own = (lane < nb) ? bsum[lane] : 0;
  int v = own;
  for (int off = 1; off < 64; off <<= 1) {
    int x = __shfl_up(v, off);
    if (lane >= off) v += x;
  }
  if (lane < nb) bscan[lane] = v - own;
  if (lane == 0) rowptr[0] = 0;
}
__global__ void k_s3(const int* __restrict__ bscan, int* __restrict__ rowptr) {
  int i = blockIdx.x * 1024 + threadIdx.x;
  if (i < N_NODES && blockIdx.x > 0) rowptr[i + 1] += bscan[blockIdx.x];
}

__global__ void k_scatter(const int* __restrict__ src, const int* __restrict__ dst,
                          const int* __restrict__ et, const int* __restrict__ rowptr,
                          int* __restrict__ cursor, const int* __restrict__ cnt,
                          int* __restrict__ es_src, int* __restrict__ es_rel,
                          float* __restrict__ es_w, int E) {
  int e = blockIdx.x * 256 + threadIdx.x;
  if (e < E) {
    int d = dst[e], r = et[e], s = src[e];
    int pos = atomicAdd(&cursor[d], 1);
    int idx = rowptr[d] + pos;
    es_src[idx] = s;
    es_rel[idx] = r;
    es_w[idx] = 1.0f / (float)cnt[r * N_NODES + d];
  }
}

// ---------- packs (single fp16) ----------
__global__ void k_pack_x(const float* __restrict__ x, uint16_t* __restrict__ xh) {
  long long i = (long long)blockIdx.x * 256 + threadIdx.x;
  if (i >= (long long)MPAD * KPAD) return;
  int n = (int)(i / KPAD), k = (int)(i % KPAD);
  float v = (n < N_NODES && k < DIN) ? x[(long long)n * DIN + k] : 0.0f;
  xh[i] = f2h(v);
}

__global__ void k_pack_b1(const float* __restrict__ W1, const float* __restrict__ root1,
                          uint16_t* __restrict__ Bh) {
  long long i = (long long)blockIdx.x * 256 + threadIdx.x;
  if (i >= (long long)NCOL1 * KPAD) return;
  int c = (int)(i / KPAD), k = (int)(i % KPAD);
  float v = 0.0f;
  if (k < DIN) {
    if (c < NREL * H1) {
      int r = c >> 8, j = c & 255;
      v = W1[((long long)r * DIN + k) * H1 + j];
    } else {
      v = root1[(long long)k * H1 + (c - NREL * H1)];
    }
  }
  Bh[i] = f2h(v);
}

__global__ void k_pack_b2(const float* __restrict__ W2, const float* __restrict__ root2,
                          uint16_t* __restrict__ b2h) {
  int i = blockIdx.x * 256 + threadIdx.x;
  if (i >= N2PAD * H1) return;
  int c = i >> 8, k = i & 255;
  float v = 0.0f;
  if (c < 2 * NREL) { int r = c >> 1, j = c & 1; v = W2[(r * H1 + k) * 2 + j]; }
  else if (c < Y2C) v = root2[k * 2 + (c - 2 * NREL)];
  b2h[i] = f2h(v);
}

// ---------- layer-1 GEMM (fp16 single-term): C[m,c] = sum_k A[m,k]*B[c,k] ----------
// LDS tiles [128 rows][32 k] with XOR bank-swizzle: 16B chunk c of row r lives at
// slot c ^ ((r>>1)&3). Written via pre-swizzled GLOBAL source (rule 21), read with
// the same XOR. Grid: 1D, bijective XCD-contiguous swizzle, m-slow / y-fast.
__global__ __launch_bounds__(256) void k_gemm1(
    const uint16_t* __restrict__ A, const uint16_t* __restrict__ B,
    uint16_t* __restrict__ C, int ldc) {
  __shared__ __align__(16) uint16_t sA[128 * 32];
  __shared__ __align__(16) uint16_t sB[128 * 32];
  int tid = threadIdx.x;
  int lane = tid & 63, w = tid >> 6;
  int wr = w >> 1, wc = w & 1;

  // XCD-contiguous bijective swizzle (m204 form), then m = wg/nyt (slow), y = wg%nyt
  int nyt = ldc >> 7;
  int nwg = gridDim.x;
  int f = blockIdx.x;
  int q = nwg >> 3, r = nwg & 7;
  int xcd = f & 7, idx = f >> 3;
  int wg = (xcd < r ? xcd * (q + 1) : r * (q + 1) + (xcd - r) * q) + idx;
  int mt = wg / nyt, yt = wg - mt * nyt;
  long long bm = (long long)mt * 128;
  long long bn = (long long)yt * 128;

  f4v zero = {0.f, 0.f, 0.f, 0.f};
  f4v acc[4][4];
#pragma unroll
  for (int i = 0; i < 4; ++i)
#pragma unroll
    for (int j = 0; j < 4; ++j) acc[i][j] = zero;

  int lrow = lane & 15;
  // read-side swizzled k-offset (elements): (q ^ ((lrow>>1)&3)) * 8
  int lko = (((lane >> 4) ^ ((lane >> 1) & 3)) * 8);
  // write-side: lane l stages LDS slot (row, l&3); source global chunk = (l&3)^((row>>1)&3)
  // row = w*32 + j*16 + (l>>2)  =>  (row>>1)&3 == (l>>3)&3  (w*16, j*8 are 0 mod 4)
  int srow0 = w * 32 + (lane >> 2);
  int srow1 = srow0 + 16;
  int skel = (((lane & 3) ^ ((lane >> 3) & 3)) * 8);

  for (int kk = 0; kk < KPAD; kk += 32) {
    gload16(A + (bm + srow0) * KPAD + kk + skel, sA + w * 1024);
    gload16(A + (bm + srow1) * KPAD + kk + skel, sA + w * 1024 + 512);
    gload16(B + (bn + srow0) * KPAD + kk + skel, sB + w * 1024);
    gload16(B + (bn + srow1) * KPAD + kk + skel, sB + w * 1024 + 512);
    __syncthreads();

    s8v af[4], bfr[4];
#pragma unroll
    for (int mi = 0; mi < 4; ++mi)
      af[mi] = *(const s8v*)(sA + (wr * 64 + mi * 16 + lrow) * 32 + lko);
#pragma unroll
    for (int ni = 0; ni < 4; ++ni)
      bfr[ni] = *(const s8v*)(sB + (wc * 64 + ni * 16 + lrow) * 32 + lko);
#pragma unroll
    for (int mi = 0; mi < 4; ++mi)
#pragma unroll
      for (int ni = 0; ni < 4; ++ni)
        acc[mi][ni] = mfma_f16(af[mi], bfr[ni], acc[mi][ni]);
    __syncthreads();
  }
  int rg = (lane >> 4) * 4;
#pragma unroll
  for (int mi = 0; mi < 4; ++mi) {
#pragma unroll
    for (int ni = 0; ni < 4; ++ni) {
      long long col = bn + wc * 64 + ni * 16 + (lane & 15);
#pragma unroll
      for (int r2 = 0; r2 < 4; ++r2) {
        long long row = bm + wr * 64 + mi * 16 + rg + r2;
        C[row * ldc + col] = f2h(acc[mi][ni][r2]);
      }
    }
  }
}

// ---------- aggregation 1: wave-per-node, metadata prefetch + shfl broadcast ----------
__global__ __launch_bounds__(256) void k_agg1(
    const uint16_t* __restrict__ y1,   // fp16 chunk [MPAD][ldy]
    const int* __restrict__ es_src, const int* __restrict__ es_rel,
    const float* __restrict__ es_w, const int* __restrict__ rowptr,
    float* __restrict__ h, int r0, int nb, int ldy) {
  int n = blockIdx.x * 4 + (threadIdx.x >> 6);
  int lane = threadIdx.x & 63;
  if (n >= N_NODES) return;
  int e0 = rowptr[n], e1 = rowptr[n + 1];
  int deg = e1 - e0;
  float4 acc = {0.f, 0.f, 0.f, 0.f};

  int mrel = -1000, msrc = 0;
  float mw = 0.f;
  if (lane < deg) {
    int e = e0 + lane;
    mrel = es_rel[e] - r0;
    msrc = es_src[e];
    mw = es_w[e];
  }
  int dcap = deg <= 64 ? deg : 64;
  for (int j = 0; j < dcap; ++j) {
    int off = __shfl(mrel, j);
    if ((unsigned)off < (unsigned)nb) {
      int s = __shfl(msrc, j);
      float wgt = __shfl(mw, j);
      uint2 v = *(const uint2*)(y1 + (long long)s * ldy + off * H1 + lane * 4);
      acc.x += wgt * h2f((uint16_t)v.x);
      acc.y += wgt * h2f((uint16_t)(v.x >> 16));
      acc.z += wgt * h2f((uint16_t)v.y);
      acc.w += wgt * h2f((uint16_t)(v.y >> 16));
    }
  }
  for (int e = e0 + 64; e < e1; ++e) {
    int off = es_rel[e] - r0;
    if ((unsigned)off < (unsigned)nb) {
      int s = es_src[e];
      float wgt = es_w[e];
      uint2 v = *(const uint2*)(y1 + (long long)s * ldy + off * H1 + lane * 4);
      acc.x += wgt * h2f((uint16_t)v.x);
      acc.y += wgt * h2f((uint16_t)(v.x >> 16));
      acc.z += wgt * h2f((uint16_t)v.y);
      acc.w += wgt * h2f((uint16_t)(v.y >> 16));
    }
  }
  if (r0 <= NREL && NREL < r0 + nb) {
    uint2 v = *(const uint2*)(y1 + (long long)n * ldy + (NREL - r0) * H1 + lane * 4);
    acc.x += h2f((uint16_t)v.x);
    acc.y += h2f((uint16_t)(v.x >> 16));
    acc.z += h2f((uint16_t)v.y);
    acc.w += h2f((uint16_t)(v.y >> 16));
  }
  float* hp = h + (long long)n * H1 + lane * 4;
  float4 old = *(const float4*)hp;
  old.x += acc.x; old.y += acc.y; old.z += acc.z; old.w += acc.w;
  *(float4*)hp = old;
}

// ---------- fin1: bias+relu, emit h as single fp16 (rows padded to MPAD) ----------
__global__ void k_fin1h(const float* __restrict__ h, const float* __restrict__ b1,
                        uint16_t* __restrict__ h16) {
  long long i = (long long)blockIdx.x * 256 + threadIdx.x;
  if (i >= (long long)MPAD * H1) return;
  int n = (int)(i >> 8), c = (int)(i & 255);
  float v = 0.0f;
  if (n < N_NODES) {
    v = h[i] + b1[c];
    v = v > 0.f ? v : 0.f;
  }
  h16[i] = f2h(v);
}

// ---------- layer-2 transform via MFMA (fp16 single): y2[M, 34] = h @ B2^T ----------
__global__ __launch_bounds__(256) void k_gemm2m(
    const uint16_t* __restrict__ h16, const uint16_t* __restrict__ b2h,
    float* __restrict__ y2) {
  __shared__ __align__(16) uint16_t sB[N2PAD * LDB2];
  __shared__ __align__(16) uint16_t sA[128 * 32];
  int tid = threadIdx.x, lane = tid & 63, w = tid >> 6;
  long long bm = (long long)blockIdx.x * 128;

  for (int cid = tid; cid < N2PAD * 32; cid += 256) {
    int row = cid >> 5, off = cid & 31;
    *(uint4*)(&sB[row * LDB2 + off * 8]) = *(const uint4*)(b2h + row * H1 + off * 8);
  }

  f4v zero = {0.f, 0.f, 0.f, 0.f};
  f4v acc[2][3];
#pragma unroll
  for (int i = 0; i < 2; ++i)
#pragma unroll
    for (int j = 0; j < 3; ++j) acc[i][j] = zero;

  int lrow = lane & 15;
  int lko = (((lane >> 4) ^ ((lane >> 1) & 3)) * 8);
  int srow0 = w * 32 + (lane >> 2), srow1 = srow0 + 16;
  int skel = (((lane & 3) ^ ((lane >> 3) & 3)) * 8);

  for (int kk = 0; kk < H1; kk += 32) {
    gload16(h16 + (bm + srow0) * H1 + kk + skel, sA + w * 1024);
    gload16(h16 + (bm + srow1) * H1 + kk + skel, sA + w * 1024 + 512);
    __syncthreads();

    s8v ah[2];
#pragma unroll
    for (int mi = 0; mi < 2; ++mi)
      ah[mi] = *(const s8v*)(sA + (w * 32 + mi * 16 + lrow) * 32 + lko);
#pragma unroll
    for (int nj = 0; nj < 3; ++nj) {
      s8v bh = *(const s8v*)(&sB[(nj * 16 + lrow) * LDB2 + kk + ((lane >> 4) * 8)]);
#pragma unroll
      for (int mi = 0; mi < 2; ++mi)
        acc[mi][nj] = mfma_f16(ah[mi], bh, acc[mi][nj]);
    }
    __syncthreads();
  }
  int rg = (lane >> 4) * 4;
#pragma unroll
  for (int mi = 0; mi < 2; ++mi) {
#pragma unroll
    for (int nj = 0; nj < 3; ++nj) {
      int col = nj * 16 + (lane & 15);
      if (col < Y2C) {
#pragma unroll
        for (int r2 = 0; r2 < 4; ++r2) {
          long long row = bm + w * 32 + mi * 16 + rg + r2;
          if (row < N_NODES) y2[row * Y2C + col] = acc[mi][nj][r2];
        }
      }
    }
  }
}

// ---------- aggregation 2 + tanh ----------
__global__ void k_agg2(const float* __restrict__ y2, const int* __restrict__ es_src,
                       const int* __restrict__ es_rel, const float* __restrict__ es_w,
                       const int* __restrict__ rowptr, const float* __restrict__ b2,
                       float* __restrict__ out) {
  int n = blockIdx.x * 4 + (threadIdx.x >> 6);
  int lane = threadIdx.x & 63;
  if (n >= N_NODES) return;
  float a0 = 0.f, a1 = 0.f;
  int e0 = rowptr[n], e1 = rowptr[n + 1];
  for (int e = e0 + lane; e < e1; e += 64) {
    int s = es_src[e], r = es_rel[e];
    float wgt = es_w[e];
    a0 += wgt * y2[s * Y2C + r * 2];
    a1 += wgt * y2[s * Y2C + r * 2 + 1];
  }
#pragma unroll
  for (int off = 32; off > 0; off >>= 1) {
    a0 += __shfl_down(a0, off);
    a1 += __shfl_down(a1, off);
  }
  if (lane == 0) {
    a0 += y2[n * Y2C + 2 * NREL] + b2[0];
    a1 += y2[n * Y2C + 2 * NREL + 1] + b2[1];
    out[n * 2] = tanhf(a0);
    out[n * 2 + 1] = tanhf(a1);
  }
}

extern "C" void kernel_launch(void* const* d_in, const int* in_sizes, int n_in,
                              void* d_out, int out_size, void* d_ws, size_t ws_size,
                              hipStream_t stream) {
  const float* x     = (const float*)d_in[0];
  const int*   ei    = (const int*)d_in[1];
  const int*   et    = (const int*)d_in[2];
  const float* W1    = (const float*)d_in[3];
  const float* root1 = (const float*)d_in[4];
  const float* b1    = (const float*)d_in[5];
  const float* W2    = (const float*)d_in[6];
  const float* root2 = (const float*)d_in[7];
  const float* b2    = (const float*)d_in[8];
  const int E = in_sizes[2];
  const int* src = ei;
  const int* dst = ei + E;

  char* ws = (char*)d_ws;
  size_t off = 0;
  auto alloc = [&](size_t bytes) {
    size_t o = off; off += (bytes + 255) & ~(size_t)255; return o;
  };
  size_t o_cnt = alloc((size_t)NREL * N_NODES * 4);
  size_t o_deg = alloc((size_t)(N_NODES + 1) * 4);
  size_t o_cur = alloc((size_t)N_NODES * 4);
  size_t o_h   = alloc((size_t)N_NODES * H1 * 4);
  size_t zero_bytes = off;
  size_t o_rp   = alloc((size_t)(N_NODES + 1) * 4);
  size_t o_bsum = alloc(64 * 4);
  size_t o_bscn = alloc(64 * 4);
  size_t o_esrc = alloc((size_t)E * 4);
  size_t o_erel = alloc((size_t)E * 4);
  size_t o_ew   = alloc((size_t)E * 4);
  size_t o_xh   = alloc((size_t)MPAD * KPAD * 2);   // h16 aliases this later
  size_t o_b1h  = alloc((size_t)NCOL1 * KPAD * 2);
  size_t o_b2h  = alloc((size_t)N2PAD * H1 * 2);
  size_t o_y2   = alloc((size_t)N_NODES * Y2C * 4);
  size_t o_y1   = off;  // rest of ws: y1 chunk buffer (fp16)

  int*      cnt  = (int*)(ws + o_cnt);
  int*      deg  = (int*)(ws + o_deg);
  int*      cur  = (int*)(ws + o_cur);
  float*    h    = (float*)(ws + o_h);
  int*      rp   = (int*)(ws + o_rp);
  int*      bsum = (int*)(ws + o_bsum);
  int*      bscn = (int*)(ws + o_bscn);
  int*      esrc = (int*)(ws + o_esrc);
  int*      erel = (int*)(ws + o_erel);
  float*    ew   = (float*)(ws + o_ew);
  uint16_t* xh   = (uint16_t*)(ws + o_xh);
  uint16_t* b1h  = (uint16_t*)(ws + o_b1h);
  uint16_t* b2h  = (uint16_t*)(ws + o_b2h);
  // h16 aliases xh: xh dead after last k_gemm1; fin1h writes strictly later.
  uint16_t* h16  = (uint16_t*)(ws + o_xh);
  float*    y2   = (float*)(ws + o_y2);
  uint16_t* y1   = (uint16_t*)(ws + o_y1);

  size_t per_block = (size_t)MPAD * H1 * 2;  // one 256-col fp16 y1 block
  int G = 1;
  if (ws_size > o_y1 + per_block) {
    size_t g = (ws_size - o_y1) / per_block;
    G = (int)(g > (size_t)NB1 ? (size_t)NB1 : g);
  }

  const int NSB = (N_NODES + 1023) / 1024;

  hipMemsetAsync(ws, 0, zero_bytes, stream);
  k_count<<<(E + 255) / 256, 256, 0, stream>>>(dst, et, deg, cnt, E);
  k_s1<<<NSB, 1024, 0, stream>>>(deg, rp, bsum);
  k_s2<<<1, 64, 0, stream>>>(bsum, bscn, rp, NSB);
  k_s3<<<NSB, 1024, 0, stream>>>(bscn, rp);
  k_scatter<<<(E + 255) / 256, 256, 0, stream>>>(src, dst, et, rp, cur, cnt,
                                                 esrc, erel, ew, E);
  k_pack_x<<<(unsigned)(((long long)MPAD * KPAD + 255) / 256), 256, 0, stream>>>(x, xh);
  k_pack_b1<<<(unsigned)(((long long)NCOL1 * KPAD + 255) / 256), 256, 0, stream>>>(W1, root1, b1h);
  k_pack_b2<<<(N2PAD * H1 + 255) / 256, 256, 0, stream>>>(W2, root2, b2h);

  for (int r0 = 0; r0 < NB1; r0 += G) {
    int nb = (NB1 - r0 < G) ? (NB1 - r0) : G;
    int nyt = nb * 2;
    int nwg = (MPAD / 128) * nyt;
    k_gemm1<<<nwg, 256, 0, stream>>>(xh, b1h + (size_t)r0 * H1 * KPAD, y1, nb * H1);
    k_agg1<<<(N_NODES + 3) / 4, 256, 0, stream>>>(y1, esrc, erel, ew, rp, h,
                                                  r0, nb, nb * H1);
  }
  k_fin1h<<<(unsigned)(((long long)MPAD * H1 + 255) / 256), 256, 0, stream>>>(h, b1, h16);
  k_gemm2m<<<MPAD / 128, 256, 0, stream>>>(h16, b2h, y2);
  k_agg2<<<(N_NODES + 3) / 4, 256, 0, stream>>>(y2, esrc, erel, ew, rp, b2,
                                                (float*)d_out);
  (void)n_in; (void)out_size;
}

// Round 6
// 511.515 us; speedup vs baseline: 3.1399x; 1.0566x over previous
//
#include <hip/hip_runtime.h>
#include <cstdint>
#include <cstddef>

#define N_NODES 40000
#define DIN     386
#define H1      256
#define NREL    16
#define KPAD    416      // 13*32: zero-padded K for layer-1 GEMM
#define MPAD    40064    // 313*128: zero-padded M
#define NB1     17       // 16 relation blocks + 1 root block, 256 cols each
#define NCOL1   (NB1 * H1)      // 4352
#define Y2C     (2 * NREL + 2)  // 34
#define N2PAD   48              // Y2C padded to 3*16
#define LDB2    264             // 256 + 8 pad (2-way bank spread)

typedef __attribute__((ext_vector_type(8))) short s8v;
typedef __attribute__((ext_vector_type(4))) float f4v;

__device__ __forceinline__ uint16_t f2h(float f) {
  _Float16 h = (_Float16)f;
  return *(uint16_t*)&h;
}
__device__ __forceinline__ float h2f(uint16_t u) {
  _Float16 h = *(_Float16*)&u;
  return (float)h;
}
__device__ __forceinline__ f4v mfma_f16(s8v a, s8v b, f4v c) {
  asm("v_mfma_f32_16x16x32_f16 %0, %1, %2, %0" : "+v"(c) : "v"(a), "v"(b));
  return c;
}
__device__ __forceinline__ void gload16(const uint16_t* g, uint16_t* lds) {
  __builtin_amdgcn_global_load_lds(
      (const __attribute__((address_space(1))) unsigned int*)g,
      (__attribute__((address_space(3))) unsigned int*)lds, 16, 0, 0);
}

// ---------- CSR build ----------
__global__ void k_count(const int* __restrict__ dst, const int* __restrict__ et,
                        int* __restrict__ deg, int* __restrict__ cnt, int E) {
  int e = blockIdx.x * 256 + threadIdx.x;
  if (e < E) {
    int d = dst[e], r = et[e];
    atomicAdd(&deg[d], 1);
    atomicAdd(&cnt[r * N_NODES + d], 1);
  }
}

__global__ void k_s1(const int* __restrict__ deg, int* __restrict__ rowptr,
                     int* __restrict__ bsum) {
  __shared__ int sd[1024];
  int t = threadIdx.x;
  int i = blockIdx.x * 1024 + t;
  int v = (i < N_NODES) ? deg[i] : 0;
  sd[t] = v;
  __syncthreads();
  for (int off = 1; off < 1024; off <<= 1) {
    int x = (t >= off) ? sd[t - off] : 0;
    __syncthreads();
    sd[t] += x;
    __syncthreads();
  }
  if (i < N_NODES) rowptr[i + 1] = sd[t];
  if (t == 1023) bsum[blockIdx.x] = sd[t];
}
__global__ void k_s2(const int* __restrict__ bsum, int* __restrict__ bscan,
                     int* __restrict__ rowptr, int nb) {
  int lane = threadIdx.x & 63;
  int own = (lane < nb) ? bsum[lane] : 0;
  int v = own;
  for (int off = 1; off < 64; off <<= 1) {
    int x = __shfl_up(v, off);
    if (lane >= off) v += x;
  }
  if (lane < nb) bscan[lane] = v - own;
  if (lane == 0) rowptr[0] = 0;
}
__global__ void k_s3(const int* __restrict__ bscan, int* __restrict__ rowptr) {
  int i = blockIdx.x * 1024 + threadIdx.x;
  if (i < N_NODES && blockIdx.x > 0) rowptr[i + 1] += bscan[blockIdx.x];
}

__global__ void k_scatter(const int* __restrict__ src, const int* __restrict__ dst,
                          const int* __restrict__ et, const int* __restrict__ rowptr,
                          int* __restrict__ cursor, const int* __restrict__ cnt,
                          int* __restrict__ es_src, int* __restrict__ es_rel,
                          float* __restrict__ es_w, int E) {
  int e = blockIdx.x * 256 + threadIdx.x;
  if (e < E) {
    int d = dst[e], r = et[e], s = src[e];
    int pos = atomicAdd(&cursor[d], 1);
    int idx = rowptr[d] + pos;
    es_src[idx] = s;
    es_rel[idx] = r;
    es_w[idx] = 1.0f / (float)cnt[r * N_NODES + d];
  }
}

// ---------- packs (single fp16) ----------
__global__ void k_pack_x(const float* __restrict__ x, uint16_t* __restrict__ xh) {
  long long i = (long long)blockIdx.x * 256 + threadIdx.x;
  if (i >= (long long)MPAD * KPAD) return;
  int n = (int)(i / KPAD), k = (int)(i % KPAD);
  float v = (n < N_NODES && k < DIN) ? x[(long long)n * DIN + k] : 0.0f;
  xh[i] = f2h(v);
}

__global__ void k_pack_b1(const float* __restrict__ W1, const float* __restrict__ root1,
                          uint16_t* __restrict__ Bh) {
  long long i = (long long)blockIdx.x * 256 + threadIdx.x;
  if (i >= (long long)NCOL1 * KPAD) return;
  int c = (int)(i / KPAD), k = (int)(i % KPAD);
  float v = 0.0f;
  if (k < DIN) {
    if (c < NREL * H1) {
      int r = c >> 8, j = c & 255;
      v = W1[((long long)r * DIN + k) * H1 + j];
    } else {
      v = root1[(long long)k * H1 + (c - NREL * H1)];
    }
  }
  Bh[i] = f2h(v);
}

__global__ void k_pack_b2(const float* __restrict__ W2, const float* __restrict__ root2,
                          uint16_t* __restrict__ b2h) {
  int i = blockIdx.x * 256 + threadIdx.x;
  if (i >= N2PAD * H1) return;
  int c = i >> 8, k = i & 255;
  float v = 0.0f;
  if (c < 2 * NREL) { int r = c >> 1, j = c & 1; v = W2[(r * H1 + k) * 2 + j]; }
  else if (c < Y2C) v = root2[k * 2 + (c - 2 * NREL)];
  b2h[i] = f2h(v);
}

// ---------- layer-1 GEMM (fp16, double-buffered, counted vmcnt) ----------
// LDS: 2 bufs x (A,B) x [128][32] fp16, XOR bank-swizzled (round-5 scheme, verified
// conflict-free). K-loop per iter: stage(next buf) -> vmcnt(4) [cur's 4 loads done,
// next's stay IN FLIGHT across both barriers: T4] -> barrier -> ds_read+MFMA ->
// barrier [protects cur before it's overwritten next iter].
__global__ __launch_bounds__(256) void k_gemm1(
    const uint16_t* __restrict__ A, const uint16_t* __restrict__ B,
    uint16_t* __restrict__ C, int ldc) {
  __shared__ __align__(16) uint16_t smem[4][128 * 32];  // [0,1]=A bufs, [2,3]=B bufs
  int tid = threadIdx.x;
  int lane = tid & 63, w = tid >> 6;
  int wr = w >> 1, wc = w & 1;

  // bijective XCD-contiguous swizzle (m204 form); m slow, col-tile fast
  int nyt = ldc >> 7;
  int nwg = gridDim.x;
  int f = blockIdx.x;
  int q = nwg >> 3, r = nwg & 7;
  int xcd = f & 7, idx = f >> 3;
  int wg = (xcd < r ? xcd * (q + 1) : r * (q + 1) + (xcd - r) * q) + idx;
  int mt = wg / nyt, yt = wg - mt * nyt;
  long long bm = (long long)mt * 128;
  long long bn = (long long)yt * 128;

  int lrow = lane & 15;
  int lko = (((lane >> 4) ^ ((lane >> 1) & 3)) * 8);     // read-side swizzle
  int srow0 = w * 32 + (lane >> 2);
  int srow1 = srow0 + 16;
  int skel = (((lane & 3) ^ ((lane >> 3) & 3)) * 8);     // write-side (pre-swz global)

  const uint16_t* gA0 = A + (bm + srow0) * KPAD + skel;
  const uint16_t* gA1 = A + (bm + srow1) * KPAD + skel;
  const uint16_t* gB0 = B + (bn + srow0) * KPAD + skel;
  const uint16_t* gB1 = B + (bn + srow1) * KPAD + skel;

  f4v zero = {0.f, 0.f, 0.f, 0.f};
  f4v acc[4][4];
#pragma unroll
  for (int i = 0; i < 4; ++i)
#pragma unroll
    for (int j = 0; j < 4; ++j) acc[i][j] = zero;

  // prologue: stage tile 0 into buf 0
  gload16(gA0, smem[0] + w * 1024);
  gload16(gA1, smem[0] + w * 1024 + 512);
  gload16(gB0, smem[2] + w * 1024);
  gload16(gB1, smem[2] + w * 1024 + 512);

  const int NIT = KPAD / 32;  // 13
  int cur = 0;
  for (int it = 0; it < NIT; ++it) {
    if (it + 1 < NIT) {
      int kk = (it + 1) * 32;
      int nxt = cur ^ 1;
      gload16(gA0 + kk, smem[nxt] + w * 1024);
      gload16(gA1 + kk, smem[nxt] + w * 1024 + 512);
      gload16(gB0 + kk, smem[2 + nxt] + w * 1024);
      gload16(gB1 + kk, smem[2 + nxt] + w * 1024 + 512);
      asm volatile("s_waitcnt vmcnt(4)" ::: "memory");  // cur ready; next in flight
    } else {
      asm volatile("s_waitcnt vmcnt(0)" ::: "memory");
    }
    __builtin_amdgcn_s_barrier();

    const uint16_t* sA = smem[cur];
    const uint16_t* sB = smem[2 + cur];
    s8v af[4], bfr[4];
#pragma unroll
    for (int mi = 0; mi < 4; ++mi)
      af[mi] = *(const s8v*)(sA + (wr * 64 + mi * 16 + lrow) * 32 + lko);
#pragma unroll
    for (int ni = 0; ni < 4; ++ni)
      bfr[ni] = *(const s8v*)(sB + (wc * 64 + ni * 16 + lrow) * 32 + lko);
#pragma unroll
    for (int mi = 0; mi < 4; ++mi)
#pragma unroll
      for (int ni = 0; ni < 4; ++ni)
        acc[mi][ni] = mfma_f16(af[mi], bfr[ni], acc[mi][ni]);

    __builtin_amdgcn_s_barrier();  // all reads of cur done before next-iter stage
    cur ^= 1;
  }

  // epilogue (round-5 layout, C/D: col=lane&15, row=(lane>>4)*4+reg)
  int rg = (lane >> 4) * 4;
#pragma unroll
  for (int mi = 0; mi < 4; ++mi) {
#pragma unroll
    for (int ni = 0; ni < 4; ++ni) {
      long long col = bn + wc * 64 + ni * 16 + (lane & 15);
#pragma unroll
      for (int r2 = 0; r2 < 4; ++r2) {
        long long row = bm + wr * 64 + mi * 16 + rg + r2;
        C[row * ldc + col] = f2h(acc[mi][ni][r2]);
      }
    }
  }
}

// ---------- aggregation 1: wave-per-node; final pass fuses bias+relu+fp16 pack ----------
__global__ __launch_bounds__(256) void k_agg1(
    const uint16_t* __restrict__ y1,   // fp16 chunk [MPAD][ldy]
    const int* __restrict__ es_src, const int* __restrict__ es_rel,
    const float* __restrict__ es_w, const int* __restrict__ rowptr,
    float* __restrict__ h, const float* __restrict__ b1,
    uint16_t* __restrict__ h16, int r0, int nb, int ldy, int fin) {
  int n = blockIdx.x * 4 + (threadIdx.x >> 6);
  int lane = threadIdx.x & 63;
  if (n >= N_NODES) return;
  int e0 = rowptr[n], e1 = rowptr[n + 1];
  int deg = e1 - e0;
  float4 acc = {0.f, 0.f, 0.f, 0.f};

  int mrel = -1000, msrc = 0;
  float mw = 0.f;
  if (lane < deg) {
    int e = e0 + lane;
    mrel = es_rel[e] - r0;
    msrc = es_src[e];
    mw = es_w[e];
  }
  int dcap = deg <= 64 ? deg : 64;
  for (int j = 0; j < dcap; ++j) {
    int off = __shfl(mrel, j);
    if ((unsigned)off < (unsigned)nb) {
      int s = __shfl(msrc, j);
      float wgt = __shfl(mw, j);
      uint2 v = *(const uint2*)(y1 + (long long)s * ldy + off * H1 + lane * 4);
      acc.x += wgt * h2f((uint16_t)v.x);
      acc.y += wgt * h2f((uint16_t)(v.x >> 16));
      acc.z += wgt * h2f((uint16_t)v.y);
      acc.w += wgt * h2f((uint16_t)(v.y >> 16));
    }
  }
  for (int e = e0 + 64; e < e1; ++e) {
    int off = es_rel[e] - r0;
    if ((unsigned)off < (unsigned)nb) {
      int s = es_src[e];
      float wgt = es_w[e];
      uint2 v = *(const uint2*)(y1 + (long long)s * ldy + off * H1 + lane * 4);
      acc.x += wgt * h2f((uint16_t)v.x);
      acc.y += wgt * h2f((uint16_t)(v.x >> 16));
      acc.z += wgt * h2f((uint16_t)v.y);
      acc.w += wgt * h2f((uint16_t)(v.y >> 16));
    }
  }
  if (r0 <= NREL && NREL < r0 + nb) {  // root block, weight 1, own row
    uint2 v = *(const uint2*)(y1 + (long long)n * ldy + (NREL - r0) * H1 + lane * 4);
    acc.x += h2f((uint16_t)v.x);
    acc.y += h2f((uint16_t)(v.x >> 16));
    acc.z += h2f((uint16_t)v.y);
    acc.w += h2f((uint16_t)(v.y >> 16));
  }
  float* hp = h + (long long)n * H1 + lane * 4;
  float4 old = *(const float4*)hp;
  old.x += acc.x; old.y += acc.y; old.z += acc.z; old.w += acc.w;
  if (fin) {
    float4 bv = *(const float4*)(b1 + lane * 4);
    float v0 = old.x + bv.x; v0 = v0 > 0.f ? v0 : 0.f;
    float v1 = old.y + bv.y; v1 = v1 > 0.f ? v1 : 0.f;
    float v2 = old.z + bv.z; v2 = v2 > 0.f ? v2 : 0.f;
    float v3 = old.w + bv.w; v3 = v3 > 0.f ? v3 : 0.f;
    uint2 o;
    o.x = (uint32_t)f2h(v0) | ((uint32_t)f2h(v1) << 16);
    o.y = (uint32_t)f2h(v2) | ((uint32_t)f2h(v3) << 16);
    *(uint2*)(h16 + (long long)n * H1 + lane * 4) = o;
  } else {
    *(float4*)hp = old;
  }
}

// ---------- layer-2 transform via MFMA (fp16): y2[M, 34] = h @ B2^T ----------
__global__ __launch_bounds__(256) void k_gemm2m(
    const uint16_t* __restrict__ h16, const uint16_t* __restrict__ b2h,
    float* __restrict__ y2) {
  __shared__ __align__(16) uint16_t sB[N2PAD * LDB2];
  __shared__ __align__(16) uint16_t sA[128 * 32];
  int tid = threadIdx.x, lane = tid & 63, w = tid >> 6;
  long long bm = (long long)blockIdx.x * 128;

  for (int cid = tid; cid < N2PAD * 32; cid += 256) {
    int row = cid >> 5, off = cid & 31;
    *(uint4*)(&sB[row * LDB2 + off * 8]) = *(const uint4*)(b2h + row * H1 + off * 8);
  }

  f4v zero = {0.f, 0.f, 0.f, 0.f};
  f4v acc[2][3];
#pragma unroll
  for (int i = 0; i < 2; ++i)
#pragma unroll
    for (int j = 0; j < 3; ++j) acc[i][j] = zero;

  int lrow = lane & 15;
  int lko = (((lane >> 4) ^ ((lane >> 1) & 3)) * 8);
  int srow0 = w * 32 + (lane >> 2), srow1 = srow0 + 16;
  int skel = (((lane & 3) ^ ((lane >> 3) & 3)) * 8);

  for (int kk = 0; kk < H1; kk += 32) {
    gload16(h16 + (bm + srow0) * H1 + kk + skel, sA + w * 1024);
    gload16(h16 + (bm + srow1) * H1 + kk + skel, sA + w * 1024 + 512);
    __syncthreads();

    s8v ah[2];
#pragma unroll
    for (int mi = 0; mi < 2; ++mi)
      ah[mi] = *(const s8v*)(sA + (w * 32 + mi * 16 + lrow) * 32 + lko);
#pragma unroll
    for (int nj = 0; nj < 3; ++nj) {
      s8v bh = *(const s8v*)(&sB[(nj * 16 + lrow) * LDB2 + kk + ((lane >> 4) * 8)]);
#pragma unroll
      for (int mi = 0; mi < 2; ++mi)
        acc[mi][nj] = mfma_f16(ah[mi], bh, acc[mi][nj]);
    }
    __syncthreads();
  }
  int rg = (lane >> 4) * 4;
#pragma unroll
  for (int mi = 0; mi < 2; ++mi) {
#pragma unroll
    for (int nj = 0; nj < 3; ++nj) {
      int col = nj * 16 + (lane & 15);
      if (col < Y2C) {
#pragma unroll
        for (int r2 = 0; r2 < 4; ++r2) {
          long long row = bm + w * 32 + mi * 16 + rg + r2;
          if (row < N_NODES) y2[row * Y2C + col] = acc[mi][nj][r2];
        }
      }
    }
  }
}

// ---------- aggregation 2 + tanh ----------
__global__ void k_agg2(const float* __restrict__ y2, const int* __restrict__ es_src,
                       const int* __restrict__ es_rel, const float* __restrict__ es_w,
                       const int* __restrict__ rowptr, const float* __restrict__ b2,
                       float* __restrict__ out) {
  int n = blockIdx.x * 4 + (threadIdx.x >> 6);
  int lane = threadIdx.x & 63;
  if (n >= N_NODES) return;
  float a0 = 0.f, a1 = 0.f;
  int e0 = rowptr[n], e1 = rowptr[n + 1];
  for (int e = e0 + lane; e < e1; e += 64) {
    int s = es_src[e], r = es_rel[e];
    float wgt = es_w[e];
    a0 += wgt * y2[s * Y2C + r * 2];
    a1 += wgt * y2[s * Y2C + r * 2 + 1];
  }
#pragma unroll
  for (int off = 32; off > 0; off >>= 1) {
    a0 += __shfl_down(a0, off);
    a1 += __shfl_down(a1, off);
  }
  if (lane == 0) {
    a0 += y2[n * Y2C + 2 * NREL] + b2[0];
    a1 += y2[n * Y2C + 2 * NREL + 1] + b2[1];
    out[n * 2] = tanhf(a0);
    out[n * 2 + 1] = tanhf(a1);
  }
}

extern "C" void kernel_launch(void* const* d_in, const int* in_sizes, int n_in,
                              void* d_out, int out_size, void* d_ws, size_t ws_size,
                              hipStream_t stream) {
  const float* x     = (const float*)d_in[0];
  const int*   ei    = (const int*)d_in[1];
  const int*   et    = (const int*)d_in[2];
  const float* W1    = (const float*)d_in[3];
  const float* root1 = (const float*)d_in[4];
  const float* b1    = (const float*)d_in[5];
  const float* W2    = (const float*)d_in[6];
  const float* root2 = (const float*)d_in[7];
  const float* b2    = (const float*)d_in[8];
  const int E = in_sizes[2];
  const int* src = ei;
  const int* dst = ei + E;

  char* ws = (char*)d_ws;
  size_t off = 0;
  auto alloc = [&](size_t bytes) {
    size_t o = off; off += (bytes + 255) & ~(size_t)255; return o;
  };
  size_t o_cnt = alloc((size_t)NREL * N_NODES * 4);
  size_t o_deg = alloc((size_t)(N_NODES + 1) * 4);
  size_t o_cur = alloc((size_t)N_NODES * 4);
  size_t o_h   = alloc((size_t)N_NODES * H1 * 4);
  size_t zero_bytes = off;
  size_t o_rp   = alloc((size_t)(N_NODES + 1) * 4);
  size_t o_bsum = alloc(64 * 4);
  size_t o_bscn = alloc(64 * 4);
  size_t o_esrc = alloc((size_t)E * 4);
  size_t o_erel = alloc((size_t)E * 4);
  size_t o_ew   = alloc((size_t)E * 4);
  size_t o_xh   = alloc((size_t)MPAD * KPAD * 2);   // h16 aliases this later
  size_t o_b1h  = alloc((size_t)NCOL1 * KPAD * 2);
  size_t o_b2h  = alloc((size_t)N2PAD * H1 * 2);
  size_t o_y2   = alloc((size_t)N_NODES * Y2C * 4);
  size_t o_y1   = off;  // rest of ws: y1 chunk buffer (fp16)

  int*      cnt  = (int*)(ws + o_cnt);
  int*      deg  = (int*)(ws + o_deg);
  int*      cur  = (int*)(ws + o_cur);
  float*    h    = (float*)(ws + o_h);
  int*      rp   = (int*)(ws + o_rp);
  int*      bsum = (int*)(ws + o_bsum);
  int*      bscn = (int*)(ws + o_bscn);
  int*      esrc = (int*)(ws + o_esrc);
  int*      erel = (int*)(ws + o_erel);
  float*    ew   = (float*)(ws + o_ew);
  uint16_t* xh   = (uint16_t*)(ws + o_xh);
  uint16_t* b1h  = (uint16_t*)(ws + o_b1h);
  uint16_t* b2h  = (uint16_t*)(ws + o_b2h);
  // h16 aliases xh: xh dead after last k_gemm1; final k_agg1 writes h16 strictly later.
  // (h16 rows >= N_NODES contain stale xh bytes; gemm2m output rows are guarded.)
  uint16_t* h16  = (uint16_t*)(ws + o_xh);
  float*    y2   = (float*)(ws + o_y2);
  uint16_t* y1   = (uint16_t*)(ws + o_y1);

  size_t per_block = (size_t)MPAD * H1 * 2;  // one 256-col fp16 y1 block
  int G = 1;
  if (ws_size > o_y1 + per_block) {
    size_t g = (ws_size - o_y1) / per_block;
    G = (int)(g > (size_t)NB1 ? (size_t)NB1 : g);
  }
  int npass = (NB1 + G - 1) / G;
  int Gb = (NB1 + npass - 1) / npass;   // balanced pass sizes (e.g. 6/6/5 not 8/8/1)

  const int NSB = (N_NODES + 1023) / 1024;

  hipMemsetAsync(ws, 0, zero_bytes, stream);
  k_count<<<(E + 255) / 256, 256, 0, stream>>>(dst, et, deg, cnt, E);
  k_s1<<<NSB, 1024, 0, stream>>>(deg, rp, bsum);
  k_s2<<<1, 64, 0, stream>>>(bsum, bscn, rp, NSB);
  k_s3<<<NSB, 1024, 0, stream>>>(bscn, rp);
  k_scatter<<<(E + 255) / 256, 256, 0, stream>>>(src, dst, et, rp, cur, cnt,
                                                 esrc, erel, ew, E);
  k_pack_x<<<(unsigned)(((long long)MPAD * KPAD + 255) / 256), 256, 0, stream>>>(x, xh);
  k_pack_b1<<<(unsigned)(((long long)NCOL1 * KPAD + 255) / 256), 256, 0, stream>>>(W1, root1, b1h);
  k_pack_b2<<<(N2PAD * H1 + 255) / 256, 256, 0, stream>>>(W2, root2, b2h);

  int r0 = 0;
  for (int p = 0; p < npass; ++p) {
    int nb = (NB1 - r0 < Gb) ? (NB1 - r0) : Gb;
    int nwg = (MPAD / 128) * nb * 2;
    k_gemm1<<<nwg, 256, 0, stream>>>(xh, b1h + (size_t)r0 * H1 * KPAD, y1, nb * H1);
    k_agg1<<<(N_NODES + 3) / 4, 256, 0, stream>>>(y1, esrc, erel, ew, rp, h, b1,
                                                  h16, r0, nb, nb * H1,
                                                  (p == npass - 1) ? 1 : 0);
    r0 += nb;
  }
  k_gemm2m<<<MPAD / 128, 256, 0, stream>>>(h16, b2h, y2);
  k_agg2<<<(N_NODES + 3) / 4, 256, 0, stream>>>(y2, esrc, erel, ew, rp, b2,
                                                (float*)d_out);
  (void)n_in; (void)out_size;
}

// Round 7
// 505.955 us; speedup vs baseline: 3.1744x; 1.0110x over previous
//
#include <hip/hip_runtime.h>
#include <cstdint>
#include <cstddef>

#define N_NODES 40000
#define DIN     386
#define H1      256
#define NREL    16
#define KPAD    416      // 13*32: zero-padded K for layer-1 GEMM
#define MPAD    40064    // 313*128: zero-padded M
#define NBREL   16       // relation column blocks (root handled separately)
#define NCOL1   ((NREL + 1) * H1)   // 4352 (incl. root block at index 16)
#define Y2C     (2 * NREL + 2)  // 34
#define N2PAD   48              // Y2C padded to 3*16
#define LDB2    264             // 256 + 8 pad (2-way bank spread)

typedef __attribute__((ext_vector_type(8))) short s8v;
typedef __attribute__((ext_vector_type(4))) float f4v;

__device__ __forceinline__ uint16_t f2h(float f) {
  _Float16 h = (_Float16)f;
  return *(uint16_t*)&h;
}
__device__ __forceinline__ float h2f(uint16_t u) {
  _Float16 h = *(_Float16*)&u;
  return (float)h;
}
__device__ __forceinline__ f4v mfma_f16(s8v a, s8v b, f4v c) {
  asm("v_mfma_f32_16x16x32_f16 %0, %1, %2, %0" : "+v"(c) : "v"(a), "v"(b));
  return c;
}
__device__ __forceinline__ void gload16(const uint16_t* g, const uint16_t* lds) {
  __builtin_amdgcn_global_load_lds(
      (const __attribute__((address_space(1))) unsigned int*)g,
      (__attribute__((address_space(3))) unsigned int*)lds, 16, 0, 0);
}

// ---------- CSR build ----------
__global__ void k_count(const int* __restrict__ dst, const int* __restrict__ et,
                        int* __restrict__ deg, int* __restrict__ cnt, int E) {
  int e = blockIdx.x * 256 + threadIdx.x;
  if (e < E) {
    int d = dst[e], r = et[e];
    atomicAdd(&deg[d], 1);
    atomicAdd(&cnt[r * N_NODES + d], 1);
  }
}

__global__ void k_s1(const int* __restrict__ deg, int* __restrict__ rowptr,
                     int* __restrict__ bsum) {
  __shared__ int sd[1024];
  int t = threadIdx.x;
  int i = blockIdx.x * 1024 + t;
  int v = (i < N_NODES) ? deg[i] : 0;
  sd[t] = v;
  __syncthreads();
  for (int off = 1; off < 1024; off <<= 1) {
    int x = (t >= off) ? sd[t - off] : 0;
    __syncthreads();
    sd[t] += x;
    __syncthreads();
  }
  if (i < N_NODES) rowptr[i + 1] = sd[t];
  if (t == 1023) bsum[blockIdx.x] = sd[t];
}
__global__ void k_s2(const int* __restrict__ bsum, int* __restrict__ bscan,
                     int* __restrict__ rowptr, int nb) {
  int lane = threadIdx.x & 63;
  int own = (lane < nb) ? bsum[lane] : 0;
  int v = own;
  for (int off = 1; off < 64; off <<= 1) {
    int x = __shfl_up(v, off);
    if (lane >= off) v += x;
  }
  if (lane < nb) bscan[lane] = v - own;
  if (lane == 0) rowptr[0] = 0;
}
__global__ void k_s3(const int* __restrict__ bscan, int* __restrict__ rowptr) {
  int i = blockIdx.x * 1024 + threadIdx.x;
  if (i < N_NODES && blockIdx.x > 0) rowptr[i + 1] += bscan[blockIdx.x];
}

__global__ void k_scatter(const int* __restrict__ src, const int* __restrict__ dst,
                          const int* __restrict__ et, const int* __restrict__ rowptr,
                          int* __restrict__ cursor, const int* __restrict__ cnt,
                          int* __restrict__ es_src, int* __restrict__ es_rel,
                          float* __restrict__ es_w, int E) {
  int e = blockIdx.x * 256 + threadIdx.x;
  if (e < E) {
    int d = dst[e], r = et[e], s = src[e];
    int pos = atomicAdd(&cursor[d], 1);
    int idx = rowptr[d] + pos;
    es_src[idx] = s;
    es_rel[idx] = r;
    es_w[idx] = 1.0f / (float)cnt[r * N_NODES + d];
  }
}

// ---------- packs (single fp16) ----------
__global__ void k_pack_x(const float* __restrict__ x, uint16_t* __restrict__ xh) {
  long long i = (long long)blockIdx.x * 256 + threadIdx.x;
  if (i >= (long long)MPAD * KPAD) return;
  int n = (int)(i / KPAD), k = (int)(i % KPAD);
  float v = (n < N_NODES && k < DIN) ? x[(long long)n * DIN + k] : 0.0f;
  xh[i] = f2h(v);
}

__global__ void k_pack_b1(const float* __restrict__ W1, const float* __restrict__ root1,
                          uint16_t* __restrict__ Bh) {
  long long i = (long long)blockIdx.x * 256 + threadIdx.x;
  if (i >= (long long)NCOL1 * KPAD) return;
  int c = (int)(i / KPAD), k = (int)(i % KPAD);
  float v = 0.0f;
  if (k < DIN) {
    if (c < NREL * H1) {
      int r = c >> 8, j = c & 255;
      v = W1[((long long)r * DIN + k) * H1 + j];
    } else {
      v = root1[(long long)k * H1 + (c - NREL * H1)];
    }
  }
  Bh[i] = f2h(v);
}

__global__ void k_pack_b2(const float* __restrict__ W2, const float* __restrict__ root2,
                          uint16_t* __restrict__ b2h) {
  int i = blockIdx.x * 256 + threadIdx.x;
  if (i >= N2PAD * H1) return;
  int c = i >> 8, k = i & 255;
  float v = 0.0f;
  if (c < 2 * NREL) { int r = c >> 1, j = c & 1; v = W2[(r * H1 + k) * 2 + j]; }
  else if (c < Y2C) v = root2[k * 2 + (c - 2 * NREL)];
  b2h[i] = f2h(v);
}

// ---------- layer-1 GEMM: 128x256 tile, 8 waves, dbuf, counted vmcnt ----------
// LDS: A dbuf 2x[128][32], B dbuf 2x[256][32], fp16, XOR bank-swizzle (verified
// round-5/6 scheme). Per iter/wave: 3 gload_lds (A 1 + B 2), vmcnt(3), barrier,
// 4+16 ds_read_b128, 32..16 MFMA per wave pair-loop, barrier.
__global__ __launch_bounds__(512) void k_gemm1(
    const uint16_t* __restrict__ A, const uint16_t* __restrict__ B,
    uint16_t* __restrict__ C, int ldc) {
  __shared__ __align__(16) uint16_t sA[2][128 * 32];
  __shared__ __align__(16) uint16_t sB[2][256 * 32];
  int tid = threadIdx.x;
  int lane = tid & 63, w = tid >> 6;
  int wr = w >> 2, wc = w & 3;    // 2M x 4N waves, wave tile 64x64

  // bijective XCD-contiguous swizzle; m slow, col-tile fast
  int nct = ldc >> 8;
  int nwg = gridDim.x;
  int f = blockIdx.x;
  int q = nwg >> 3, r = nwg & 7;
  int xcd = f & 7, idx = f >> 3;
  int wg = (xcd < r ? xcd * (q + 1) : r * (q + 1) + (xcd - r) * q) + idx;
  int mt = wg / nct, yt = wg - mt * nct;
  long long bm = (long long)mt * 128;
  long long bn = (long long)yt * 256;

  int lrow = lane & 15;
  int lko = (((lane >> 4) ^ ((lane >> 1) & 3)) * 8);   // read-side swizzle

  // staging: chunk id c -> row c>>2, swizzled k-chunk ((c&3)^((c>>3)&3)).
  // A: c = tid (512 chunks). B: c = tid and tid+512; since 512 ≡ 0 (mod 8 in
  // the (c>>3)&3 field) and (c&3) unchanged, skel is identical for both.
  int arow = tid >> 2;
  int skel = (((tid & 3) ^ ((tid >> 3) & 3)) * 8);

  const uint16_t* gA  = A + (bm + arow) * KPAD + skel;
  const uint16_t* gB0 = B + (bn + arow) * KPAD + skel;         // B rows 0..127
  const uint16_t* gB1 = B + (bn + arow + 128) * KPAD + skel;   // B rows 128..255

  f4v zero = {0.f, 0.f, 0.f, 0.f};
  f4v acc[4][4];
#pragma unroll
  for (int i = 0; i < 4; ++i)
#pragma unroll
    for (int j = 0; j < 4; ++j) acc[i][j] = zero;

  // prologue: stage tile 0 into buf 0
  gload16(gA, sA[0] + w * 512);
  gload16(gB0, sB[0] + w * 512);
  gload16(gB1, sB[0] + 4096 + w * 512);

  const int NIT = KPAD / 32;  // 13
  int cur = 0;
  for (int it = 0; it < NIT; ++it) {
    if (it + 1 < NIT) {
      int kk = (it + 1) * 32;
      int nxt = cur ^ 1;
      gload16(gA + kk, sA[nxt] + w * 512);
      gload16(gB0 + kk, sB[nxt] + w * 512);
      gload16(gB1 + kk, sB[nxt] + 4096 + w * 512);
      asm volatile("s_waitcnt vmcnt(3)" ::: "memory");  // cur done; next in flight
    } else {
      asm volatile("s_waitcnt vmcnt(0)" ::: "memory");
    }
    __builtin_amdgcn_s_barrier();

    const uint16_t* pA = sA[cur];
    const uint16_t* pB = sB[cur];
    s8v af[4];
#pragma unroll
    for (int mi = 0; mi < 4; ++mi)
      af[mi] = *(const s8v*)(pA + (wr * 64 + mi * 16 + lrow) * 32 + lko);
#pragma unroll
    for (int ni = 0; ni < 4; ++ni) {
      s8v bf = *(const s8v*)(pB + (wc * 64 + ni * 16 + lrow) * 32 + lko);
#pragma unroll
      for (int mi = 0; mi < 4; ++mi)
        acc[mi][ni] = mfma_f16(af[mi], bf, acc[mi][ni]);
    }
    __builtin_amdgcn_s_barrier();
    cur ^= 1;
  }

  int rg = (lane >> 4) * 4;
#pragma unroll
  for (int mi = 0; mi < 4; ++mi) {
#pragma unroll
    for (int ni = 0; ni < 4; ++ni) {
      long long col = bn + wc * 64 + ni * 16 + (lane & 15);
#pragma unroll
      for (int r2 = 0; r2 < 4; ++r2) {
        long long row = bm + wr * 64 + mi * 16 + rg + r2;
        C[row * ldc + col] = f2h(acc[mi][ni][r2]);
      }
    }
  }
}

// ---------- root GEMM: h[0:N_NODES, 0:256] += x @ root1 (fp32 add epilogue) ----------
__global__ __launch_bounds__(512) void k_gemmroot(
    const uint16_t* __restrict__ A, const uint16_t* __restrict__ B,
    float* __restrict__ h) {
  __shared__ __align__(16) uint16_t sA[2][128 * 32];
  __shared__ __align__(16) uint16_t sB[2][256 * 32];
  int tid = threadIdx.x;
  int lane = tid & 63, w = tid >> 6;
  int wr = w >> 2, wc = w & 3;
  long long bm = (long long)blockIdx.x * 128;

  int lrow = lane & 15;
  int lko = (((lane >> 4) ^ ((lane >> 1) & 3)) * 8);
  int arow = tid >> 2;
  int skel = (((tid & 3) ^ ((tid >> 3) & 3)) * 8);

  const uint16_t* gA  = A + (bm + arow) * KPAD + skel;
  const uint16_t* gB0 = B + arow * KPAD + skel;
  const uint16_t* gB1 = B + (arow + 128) * KPAD + skel;

  f4v zero = {0.f, 0.f, 0.f, 0.f};
  f4v acc[4][4];
#pragma unroll
  for (int i = 0; i < 4; ++i)
#pragma unroll
    for (int j = 0; j < 4; ++j) acc[i][j] = zero;

  gload16(gA, sA[0] + w * 512);
  gload16(gB0, sB[0] + w * 512);
  gload16(gB1, sB[0] + 4096 + w * 512);

  const int NIT = KPAD / 32;
  int cur = 0;
  for (int it = 0; it < NIT; ++it) {
    if (it + 1 < NIT) {
      int kk = (it + 1) * 32;
      int nxt = cur ^ 1;
      gload16(gA + kk, sA[nxt] + w * 512);
      gload16(gB0 + kk, sB[nxt] + w * 512);
      gload16(gB1 + kk, sB[nxt] + 4096 + w * 512);
      asm volatile("s_waitcnt vmcnt(3)" ::: "memory");
    } else {
      asm volatile("s_waitcnt vmcnt(0)" ::: "memory");
    }
    __builtin_amdgcn_s_barrier();

    const uint16_t* pA = sA[cur];
    const uint16_t* pB = sB[cur];
    s8v af[4];
#pragma unroll
    for (int mi = 0; mi < 4; ++mi)
      af[mi] = *(const s8v*)(pA + (wr * 64 + mi * 16 + lrow) * 32 + lko);
#pragma unroll
    for (int ni = 0; ni < 4; ++ni) {
      s8v bf = *(const s8v*)(pB + (wc * 64 + ni * 16 + lrow) * 32 + lko);
#pragma unroll
      for (int mi = 0; mi < 4; ++mi)
        acc[mi][ni] = mfma_f16(af[mi], bf, acc[mi][ni]);
    }
    __builtin_amdgcn_s_barrier();
    cur ^= 1;
  }

  int rg = (lane >> 4) * 4;
#pragma unroll
  for (int mi = 0; mi < 4; ++mi) {
#pragma unroll
    for (int ni = 0; ni < 4; ++ni) {
      int col = wc * 64 + ni * 16 + (lane & 15);
#pragma unroll
      for (int r2 = 0; r2 < 4; ++r2) {
        long long row = bm + wr * 64 + mi * 16 + rg + r2;
        if (row < N_NODES) {
          float* p = h + row * H1 + col;
          *p += acc[mi][ni][r2];
        }
      }
    }
  }
}

// ---------- aggregation 1: wave-per-node; final pass fuses bias+relu+fp16 pack ----------
__global__ __launch_bounds__(256) void k_agg1(
    const uint16_t* __restrict__ y1,   // fp16 chunk [MPAD][ldy]
    const int* __restrict__ es_src, const int* __restrict__ es_rel,
    const float* __restrict__ es_w, const int* __restrict__ rowptr,
    float* __restrict__ h, const float* __restrict__ b1,
    uint16_t* __restrict__ h16, int r0, int nb, int ldy, int fin) {
  int n = blockIdx.x * 4 + (threadIdx.x >> 6);
  int lane = threadIdx.x & 63;
  if (n >= N_NODES) return;
  int e0 = rowptr[n], e1 = rowptr[n + 1];
  int deg = e1 - e0;
  float4 acc = {0.f, 0.f, 0.f, 0.f};

  int mrel = -1000, msrc = 0;
  float mw = 0.f;
  if (lane < deg) {
    int e = e0 + lane;
    mrel = es_rel[e] - r0;
    msrc = es_src[e];
    mw = es_w[e];
  }
  int dcap = deg <= 64 ? deg : 64;
  for (int j = 0; j < dcap; ++j) {
    int off = __shfl(mrel, j);
    if ((unsigned)off < (unsigned)nb) {
      int s = __shfl(msrc, j);
      float wgt = __shfl(mw, j);
      uint2 v = *(const uint2*)(y1 + (long long)s * ldy + off * H1 + lane * 4);
      acc.x += wgt * h2f((uint16_t)v.x);
      acc.y += wgt * h2f((uint16_t)(v.x >> 16));
      acc.z += wgt * h2f((uint16_t)v.y);
      acc.w += wgt * h2f((uint16_t)(v.y >> 16));
    }
  }
  for (int e = e0 + 64; e < e1; ++e) {
    int off = es_rel[e] - r0;
    if ((unsigned)off < (unsigned)nb) {
      int s = es_src[e];
      float wgt = es_w[e];
      uint2 v = *(const uint2*)(y1 + (long long)s * ldy + off * H1 + lane * 4);
      acc.x += wgt * h2f((uint16_t)v.x);
      acc.y += wgt * h2f((uint16_t)(v.x >> 16));
      acc.z += wgt * h2f((uint16_t)v.y);
      acc.w += wgt * h2f((uint16_t)(v.y >> 16));
    }
  }
  float* hp = h + (long long)n * H1 + lane * 4;
  float4 old = *(const float4*)hp;
  old.x += acc.x; old.y += acc.y; old.z += acc.z; old.w += acc.w;
  if (fin) {
    float4 bv = *(const float4*)(b1 + lane * 4);
    float v0 = old.x + bv.x; v0 = v0 > 0.f ? v0 : 0.f;
    float v1 = old.y + bv.y; v1 = v1 > 0.f ? v1 : 0.f;
    float v2 = old.z + bv.z; v2 = v2 > 0.f ? v2 : 0.f;
    float v3 = old.w + bv.w; v3 = v3 > 0.f ? v3 : 0.f;
    uint2 o;
    o.x = (uint32_t)f2h(v0) | ((uint32_t)f2h(v1) << 16);
    o.y = (uint32_t)f2h(v2) | ((uint32_t)f2h(v3) << 16);
    *(uint2*)(h16 + (long long)n * H1 + lane * 4) = o;
  } else {
    *(float4*)hp = old;
  }
}

// ---------- layer-2 transform via MFMA (fp16): y2[M, 34] = h @ B2^T ----------
__global__ __launch_bounds__(256) void k_gemm2m(
    const uint16_t* __restrict__ h16, const uint16_t* __restrict__ b2h,
    float* __restrict__ y2) {
  __shared__ __align__(16) uint16_t sB[N2PAD * LDB2];
  __shared__ __align__(16) uint16_t sA[128 * 32];
  int tid = threadIdx.x, lane = tid & 63, w = tid >> 6;
  long long bm = (long long)blockIdx.x * 128;

  for (int cid = tid; cid < N2PAD * 32; cid += 256) {
    int row = cid >> 5, off = cid & 31;
    *(uint4*)(&sB[row * LDB2 + off * 8]) = *(const uint4*)(b2h + row * H1 + off * 8);
  }

  f4v zero = {0.f, 0.f, 0.f, 0.f};
  f4v acc[2][3];
#pragma unroll
  for (int i = 0; i < 2; ++i)
#pragma unroll
    for (int j = 0; j < 3; ++j) acc[i][j] = zero;

  int lrow = lane & 15;
  int lko = (((lane >> 4) ^ ((lane >> 1) & 3)) * 8);
  int srow0 = w * 32 + (lane >> 2), srow1 = srow0 + 16;
  int skel = (((lane & 3) ^ ((lane >> 3) & 3)) * 8);

  for (int kk = 0; kk < H1; kk += 32) {
    gload16(h16 + (bm + srow0) * H1 + kk + skel, sA + w * 1024);
    gload16(h16 + (bm + srow1) * H1 + kk + skel, sA + w * 1024 + 512);
    __syncthreads();

    s8v ah[2];
#pragma unroll
    for (int mi = 0; mi < 2; ++mi)
      ah[mi] = *(const s8v*)(sA + (w * 32 + mi * 16 + lrow) * 32 + lko);
#pragma unroll
    for (int nj = 0; nj < 3; ++nj) {
      s8v bh = *(const s8v*)(&sB[(nj * 16 + lrow) * LDB2 + kk + ((lane >> 4) * 8)]);
#pragma unroll
      for (int mi = 0; mi < 2; ++mi)
        acc[mi][nj] = mfma_f16(ah[mi], bh, acc[mi][nj]);
    }
    __syncthreads();
  }
  int rg = (lane >> 4) * 4;
#pragma unroll
  for (int mi = 0; mi < 2; ++mi) {
#pragma unroll
    for (int nj = 0; nj < 3; ++nj) {
      int col = nj * 16 + (lane & 15);
      if (col < Y2C) {
#pragma unroll
        for (int r2 = 0; r2 < 4; ++r2) {
          long long row = bm + w * 32 + mi * 16 + rg + r2;
          if (row < N_NODES) y2[row * Y2C + col] = acc[mi][nj][r2];
        }
      }
    }
  }
}

// ---------- aggregation 2 + tanh ----------
__global__ void k_agg2(const float* __restrict__ y2, const int* __restrict__ es_src,
                       const int* __restrict__ es_rel, const float* __restrict__ es_w,
                       const int* __restrict__ rowptr, const float* __restrict__ b2,
                       float* __restrict__ out) {
  int n = blockIdx.x * 4 + (threadIdx.x >> 6);
  int lane = threadIdx.x & 63;
  if (n >= N_NODES) return;
  float a0 = 0.f, a1 = 0.f;
  int e0 = rowptr[n], e1 = rowptr[n + 1];
  for (int e = e0 + lane; e < e1; e += 64) {
    int s = es_src[e], r = es_rel[e];
    float wgt = es_w[e];
    a0 += wgt * y2[s * Y2C + r * 2];
    a1 += wgt * y2[s * Y2C + r * 2 + 1];
  }
#pragma unroll
  for (int off = 32; off > 0; off >>= 1) {
    a0 += __shfl_down(a0, off);
    a1 += __shfl_down(a1, off);
  }
  if (lane == 0) {
    a0 += y2[n * Y2C + 2 * NREL] + b2[0];
    a1 += y2[n * Y2C + 2 * NREL + 1] + b2[1];
    out[n * 2] = tanhf(a0);
    out[n * 2 + 1] = tanhf(a1);
  }
}

extern "C" void kernel_launch(void* const* d_in, const int* in_sizes, int n_in,
                              void* d_out, int out_size, void* d_ws, size_t ws_size,
                              hipStream_t stream) {
  const float* x     = (const float*)d_in[0];
  const int*   ei    = (const int*)d_in[1];
  const int*   et    = (const int*)d_in[2];
  const float* W1    = (const float*)d_in[3];
  const float* root1 = (const float*)d_in[4];
  const float* b1    = (const float*)d_in[5];
  const float* W2    = (const float*)d_in[6];
  const float* root2 = (const float*)d_in[7];
  const float* b2    = (const float*)d_in[8];
  const int E = in_sizes[2];
  const int* src = ei;
  const int* dst = ei + E;

  char* ws = (char*)d_ws;
  size_t off = 0;
  auto alloc = [&](size_t bytes) {
    size_t o = off; off += (bytes + 255) & ~(size_t)255; return o;
  };
  size_t o_cnt = alloc((size_t)NREL * N_NODES * 4);
  size_t o_deg = alloc((size_t)(N_NODES + 1) * 4);
  size_t o_cur = alloc((size_t)N_NODES * 4);
  size_t o_h   = alloc((size_t)N_NODES * H1 * 4);
  size_t zero_bytes = off;
  size_t o_rp   = alloc((size_t)(N_NODES + 1) * 4);
  size_t o_bsum = alloc(64 * 4);
  size_t o_bscn = alloc(64 * 4);
  size_t o_esrc = alloc((size_t)E * 4);
  size_t o_erel = alloc((size_t)E * 4);
  size_t o_ew   = alloc((size_t)E * 4);
  size_t o_xh   = alloc((size_t)MPAD * KPAD * 2);   // h16 aliases this later
  size_t o_b1h  = alloc((size_t)NCOL1 * KPAD * 2);
  size_t o_b2h  = alloc((size_t)N2PAD * H1 * 2);
  size_t o_y2   = alloc((size_t)N_NODES * Y2C * 4);
  size_t o_y1   = off;  // rest of ws: y1 chunk buffer (fp16)

  int*      cnt  = (int*)(ws + o_cnt);
  int*      deg  = (int*)(ws + o_deg);
  int*      cur  = (int*)(ws + o_cur);
  float*    h    = (float*)(ws + o_h);
  int*      rp   = (int*)(ws + o_rp);
  int*      bsum = (int*)(ws + o_bsum);
  int*      bscn = (int*)(ws + o_bscn);
  int*      esrc = (int*)(ws + o_esrc);
  int*      erel = (int*)(ws + o_erel);
  float*    ew   = (float*)(ws + o_ew);
  uint16_t* xh   = (uint16_t*)(ws + o_xh);
  uint16_t* b1h  = (uint16_t*)(ws + o_b1h);
  uint16_t* b2h  = (uint16_t*)(ws + o_b2h);
  // h16 aliases xh: xh dead after last GEMM; final k_agg1 writes h16 strictly later.
  uint16_t* h16  = (uint16_t*)(ws + o_xh);
  float*    y2   = (float*)(ws + o_y2);
  uint16_t* y1   = (uint16_t*)(ws + o_y1);

  size_t per_block = (size_t)MPAD * H1 * 2;  // one 256-col fp16 y1 block
  int G = 1;
  if (ws_size > o_y1 + per_block) {
    size_t g = (ws_size - o_y1) / per_block;
    G = (int)(g > (size_t)NBREL ? (size_t)NBREL : g);
  }
  int npass = (NBREL + G - 1) / G;
  int Gb = (NBREL + npass - 1) / npass;   // balanced pass sizes (6,6,4 at G=6)

  const int NSB = (N_NODES + 1023) / 1024;

  hipMemsetAsync(ws, 0, zero_bytes, stream);
  k_count<<<(E + 255) / 256, 256, 0, stream>>>(dst, et, deg, cnt, E);
  k_s1<<<NSB, 1024, 0, stream>>>(deg, rp, bsum);
  k_s2<<<1, 64, 0, stream>>>(bsum, bscn, rp, NSB);
  k_s3<<<NSB, 1024, 0, stream>>>(bscn, rp);
  k_scatter<<<(E + 255) / 256, 256, 0, stream>>>(src, dst, et, rp, cur, cnt,
                                                 esrc, erel, ew, E);
  k_pack_x<<<(unsigned)(((long long)MPAD * KPAD + 255) / 256), 256, 0, stream>>>(x, xh);
  k_pack_b1<<<(unsigned)(((long long)NCOL1 * KPAD + 255) / 256), 256, 0, stream>>>(W1, root1, b1h);
  k_pack_b2<<<(N2PAD * H1 + 255) / 256, 256, 0, stream>>>(W2, root2, b2h);

  // root contribution straight into h (before any agg1 pass touches h further)
  k_gemmroot<<<MPAD / 128, 512, 0, stream>>>(xh, b1h + (size_t)NREL * H1 * KPAD, h);

  int r0 = 0;
  for (int p = 0; p < npass; ++p) {
    int nb = (NBREL - r0 < Gb) ? (NBREL - r0) : Gb;
    int nwg = (MPAD / 128) * nb;           // BN=256: one col-tile per relation block
    k_gemm1<<<nwg, 512, 0, stream>>>(xh, b1h + (size_t)r0 * H1 * KPAD, y1, nb * H1);
    k_agg1<<<(N_NODES + 3) / 4, 256, 0, stream>>>(y1, esrc, erel, ew, rp, h, b1,
                                                  h16, r0, nb, nb * H1,
                                                  (p == npass - 1) ? 1 : 0);
    r0 += nb;
  }
  k_gemm2m<<<MPAD / 128, 256, 0, stream>>>(h16, b2h, y2);
  k_agg2<<<(N_NODES + 3) / 4, 256, 0, stream>>>(y2, esrc, erel, ew, rp, b2,
                                                (float*)d_out);
  (void)n_in; (void)out_size;
}

// Round 8
// 474.639 us; speedup vs baseline: 3.3838x; 1.0660x over previous
//
#include <hip/hip_runtime.h>
#include <cstdint>
#include <cstddef>

#define N_NODES 40000
#define DIN     386
#define H1      256
#define NREL    16
#define KPAD    416      // 13*32: zero-padded K for layer-1 GEMM
#define MPAD    40064    // 313*128: zero-padded M
#define NBREL   16       // relation column blocks (root handled separately)
#define NCOL1   ((NREL + 1) * H1)   // 4352 (incl. root block at index 16)
#define Y2C     (2 * NREL + 2)  // 34
#define N2PAD   48              // Y2C padded to 3*16
#define LDB2    264             // 256 + 8 pad (2-way bank spread)

typedef __attribute__((ext_vector_type(8))) short s8v;
typedef __attribute__((ext_vector_type(4))) float f4v;

__device__ __forceinline__ uint16_t f2h(float f) {
  _Float16 h = (_Float16)f;
  return *(uint16_t*)&h;
}
__device__ __forceinline__ float h2f(uint16_t u) {
  _Float16 h = *(_Float16*)&u;
  return (float)h;
}
__device__ __forceinline__ f4v mfma_f16(s8v a, s8v b, f4v c) {
  asm("v_mfma_f32_16x16x32_f16 %0, %1, %2, %0" : "+v"(c) : "v"(a), "v"(b));
  return c;
}
__device__ __forceinline__ void gload16(const uint16_t* g, const uint16_t* lds) {
  __builtin_amdgcn_global_load_lds(
      (const __attribute__((address_space(1))) unsigned int*)g,
      (__attribute__((address_space(3))) unsigned int*)lds, 16, 0, 0);
}

// ---------- CSR build ----------
__global__ void k_count(const int* __restrict__ dst, const int* __restrict__ et,
                        int* __restrict__ deg, int* __restrict__ cnt, int E) {
  int e = blockIdx.x * 256 + threadIdx.x;
  if (e < E) {
    int d = dst[e], r = et[e];
    atomicAdd(&deg[d], 1);
    atomicAdd(&cnt[r * N_NODES + d], 1);
  }
}

__global__ void k_s1(const int* __restrict__ deg, int* __restrict__ rowptr,
                     int* __restrict__ bsum) {
  __shared__ int sd[1024];
  int t = threadIdx.x;
  int i = blockIdx.x * 1024 + t;
  int v = (i < N_NODES) ? deg[i] : 0;
  sd[t] = v;
  __syncthreads();
  for (int off = 1; off < 1024; off <<= 1) {
    int x = (t >= off) ? sd[t - off] : 0;
    __syncthreads();
    sd[t] += x;
    __syncthreads();
  }
  if (i < N_NODES) rowptr[i + 1] = sd[t];
  if (t == 1023) bsum[blockIdx.x] = sd[t];
}
__global__ void k_s2(const int* __restrict__ bsum, int* __restrict__ bscan,
                     int* __restrict__ rowptr, int nb) {
  int lane = threadIdx.x & 63;
  int own = (lane < nb) ? bsum[lane] : 0;
  int v = own;
  for (int off = 1; off < 64; off <<= 1) {
    int x = __shfl_up(v, off);
    if (lane >= off) v += x;
  }
  if (lane < nb) bscan[lane] = v - own;
  if (lane == 0) rowptr[0] = 0;
}
__global__ void k_s3(const int* __restrict__ bscan, int* __restrict__ rowptr) {
  int i = blockIdx.x * 1024 + threadIdx.x;
  if (i < N_NODES && blockIdx.x > 0) rowptr[i + 1] += bscan[blockIdx.x];
}

__global__ void k_scatter(const int* __restrict__ src, const int* __restrict__ dst,
                          const int* __restrict__ et, const int* __restrict__ rowptr,
                          int* __restrict__ cursor, const int* __restrict__ cnt,
                          int* __restrict__ es_src, int* __restrict__ es_rel,
                          float* __restrict__ es_w, int E) {
  int e = blockIdx.x * 256 + threadIdx.x;
  if (e < E) {
    int d = dst[e], r = et[e], s = src[e];
    int pos = atomicAdd(&cursor[d], 1);
    int idx = rowptr[d] + pos;
    es_src[idx] = s;
    es_rel[idx] = r;
    es_w[idx] = 1.0f / (float)cnt[r * N_NODES + d];
  }
}

// ---------- packs (single fp16) ----------
// pair-vectorized: thread handles (n, 2k..2k+1); DIN=386 even -> pairs never straddle
__global__ void k_pack_x(const float* __restrict__ x, uint16_t* __restrict__ xh) {
  long long i = (long long)blockIdx.x * 256 + threadIdx.x;
  if (i >= (long long)MPAD * (KPAD / 2)) return;
  int n = (int)(i / (KPAD / 2)), kp = (int)(i % (KPAD / 2));
  int k = kp * 2;
  uint32_t o = 0;
  if (n < N_NODES && k + 1 < DIN) {
    float2 v = *(const float2*)(x + (long long)n * DIN + k);
    o = (uint32_t)f2h(v.x) | ((uint32_t)f2h(v.y) << 16);
  }
  *(uint32_t*)(xh + i * 2) = o;
}

__global__ void k_pack_b1(const float* __restrict__ W1, const float* __restrict__ root1,
                          uint16_t* __restrict__ Bh) {
  long long i = (long long)blockIdx.x * 256 + threadIdx.x;
  if (i >= (long long)NCOL1 * KPAD) return;
  int c = (int)(i / KPAD), k = (int)(i % KPAD);
  float v = 0.0f;
  if (k < DIN) {
    if (c < NREL * H1) {
      int r = c >> 8, j = c & 255;
      v = W1[((long long)r * DIN + k) * H1 + j];
    } else {
      v = root1[(long long)k * H1 + (c - NREL * H1)];
    }
  }
  Bh[i] = f2h(v);
}

__global__ void k_pack_b2(const float* __restrict__ W2, const float* __restrict__ root2,
                          uint16_t* __restrict__ b2h) {
  int i = blockIdx.x * 256 + threadIdx.x;
  if (i >= N2PAD * H1) return;
  int c = i >> 8, k = i & 255;
  float v = 0.0f;
  if (c < 2 * NREL) { int r = c >> 1, j = c & 1; v = W2[(r * H1 + k) * 2 + j]; }
  else if (c < Y2C) v = root2[k * 2 + (c - 2 * NREL)];
  b2h[i] = f2h(v);
}

// ---------- layer-1 GEMM: block 128x256, 4 waves, wave tile 64x128 ----------
// FLOP/LDS-byte 32 -> 42.7 vs round-7 (64x64 wave tile). acc[4][8]=128 VGPR.
// Same verified dbuf + XOR-swizzle + counted-vmcnt skeleton; 6 gloads/thread/iter.
__global__ __launch_bounds__(256) void k_gemm1(
    const uint16_t* __restrict__ A, const uint16_t* __restrict__ B,
    uint16_t* __restrict__ C, int ldc) {
  __shared__ __align__(16) uint16_t sA[2][128 * 32];
  __shared__ __align__(16) uint16_t sB[2][256 * 32];
  int tid = threadIdx.x;
  int lane = tid & 63, w = tid >> 6;
  int wr = w >> 1, wcn = w & 1;   // wave tile: rows wr*64..+63, cols wcn*128..+127

  // bijective XCD-contiguous swizzle; m slow, col-tile fast
  int nct = ldc >> 8;
  int nwg = gridDim.x;
  int f = blockIdx.x;
  int q = nwg >> 3, r = nwg & 7;
  int xcd = f & 7, idx = f >> 3;
  int wg = (xcd < r ? xcd * (q + 1) : r * (q + 1) + (xcd - r) * q) + idx;
  int mt = wg / nct, yt = wg - mt * nct;
  long long bm = (long long)mt * 128;
  long long bn = (long long)yt * 256;

  int lrow = lane & 15;
  int lko = (((lane >> 4) ^ ((lane >> 1) & 3)) * 8);   // read-side swizzle

  // staging: thread t handles chunks c = t + j*256; (c>>3)&3 and c&3 invariant
  // under +256 -> one skel serves all; rows advance by 64 per j.
  int arow = tid >> 2;                                  // 0..63
  int skel = (((tid & 3) ^ ((tid >> 3) & 3)) * 8);

  const uint16_t* gA0 = A + (bm + arow) * KPAD + skel;
  const uint16_t* gA1 = gA0 + (long long)64 * KPAD;
  const uint16_t* gB0 = B + (bn + arow) * KPAD + skel;
  const uint16_t* gB1 = gB0 + (long long)64 * KPAD;
  const uint16_t* gB2 = gB0 + (long long)128 * KPAD;
  const uint16_t* gB3 = gB0 + (long long)192 * KPAD;

  f4v zero = {0.f, 0.f, 0.f, 0.f};
  f4v acc[4][8];
#pragma unroll
  for (int i = 0; i < 4; ++i)
#pragma unroll
    for (int j = 0; j < 8; ++j) acc[i][j] = zero;

  // prologue: stage tile 0 into buf 0
  gload16(gA0, sA[0] + w * 512);
  gload16(gA1, sA[0] + 2048 + w * 512);
  gload16(gB0, sB[0] + w * 512);
  gload16(gB1, sB[0] + 2048 + w * 512);
  gload16(gB2, sB[0] + 4096 + w * 512);
  gload16(gB3, sB[0] + 6144 + w * 512);

  const int NIT = KPAD / 32;  // 13
  int cur = 0;
  for (int it = 0; it < NIT; ++it) {
    if (it + 1 < NIT) {
      int kk = (it + 1) * 32;
      int nxt = cur ^ 1;
      gload16(gA0 + kk, sA[nxt] + w * 512);
      gload16(gA1 + kk, sA[nxt] + 2048 + w * 512);
      gload16(gB0 + kk, sB[nxt] + w * 512);
      gload16(gB1 + kk, sB[nxt] + 2048 + w * 512);
      gload16(gB2 + kk, sB[nxt] + 4096 + w * 512);
      gload16(gB3 + kk, sB[nxt] + 6144 + w * 512);
      asm volatile("s_waitcnt vmcnt(6)" ::: "memory");  // cur done; next in flight
    } else {
      asm volatile("s_waitcnt vmcnt(0)" ::: "memory");
    }
    __builtin_amdgcn_s_barrier();

    const uint16_t* pA = sA[cur];
    const uint16_t* pB = sB[cur];
    s8v af[4];
#pragma unroll
    for (int mi = 0; mi < 4; ++mi)
      af[mi] = *(const s8v*)(pA + (wr * 64 + mi * 16 + lrow) * 32 + lko);
#pragma unroll
    for (int ni = 0; ni < 8; ++ni) {
      s8v bf = *(const s8v*)(pB + (wcn * 128 + ni * 16 + lrow) * 32 + lko);
#pragma unroll
      for (int mi = 0; mi < 4; ++mi)
        acc[mi][ni] = mfma_f16(af[mi], bf, acc[mi][ni]);
    }
    __builtin_amdgcn_s_barrier();
    cur ^= 1;
  }

  int rg = (lane >> 4) * 4;
#pragma unroll
  for (int mi = 0; mi < 4; ++mi) {
#pragma unroll
    for (int ni = 0; ni < 8; ++ni) {
      long long col = bn + wcn * 128 + ni * 16 + (lane & 15);
#pragma unroll
      for (int r2 = 0; r2 < 4; ++r2) {
        long long row = bm + wr * 64 + mi * 16 + rg + r2;
        C[row * ldc + col] = f2h(acc[mi][ni][r2]);
      }
    }
  }
}

// ---------- root GEMM: h[0:N_NODES, 0:256] = x @ root1 (STORE: h needs no zeroing) ----------
__global__ __launch_bounds__(512) void k_gemmroot(
    const uint16_t* __restrict__ A, const uint16_t* __restrict__ B,
    float* __restrict__ h) {
  __shared__ __align__(16) uint16_t sA[2][128 * 32];
  __shared__ __align__(16) uint16_t sB[2][256 * 32];
  int tid = threadIdx.x;
  int lane = tid & 63, w = tid >> 6;
  int wr = w >> 2, wc = w & 3;
  long long bm = (long long)blockIdx.x * 128;

  int lrow = lane & 15;
  int lko = (((lane >> 4) ^ ((lane >> 1) & 3)) * 8);
  int arow = tid >> 2;
  int skel = (((tid & 3) ^ ((tid >> 3) & 3)) * 8);

  const uint16_t* gA  = A + (bm + arow) * KPAD + skel;
  const uint16_t* gB0 = B + arow * KPAD + skel;
  const uint16_t* gB1 = B + (arow + 128) * KPAD + skel;

  f4v zero = {0.f, 0.f, 0.f, 0.f};
  f4v acc[4][4];
#pragma unroll
  for (int i = 0; i < 4; ++i)
#pragma unroll
    for (int j = 0; j < 4; ++j) acc[i][j] = zero;

  gload16(gA, sA[0] + w * 512);
  gload16(gB0, sB[0] + w * 512);
  gload16(gB1, sB[0] + 4096 + w * 512);

  const int NIT = KPAD / 32;
  int cur = 0;
  for (int it = 0; it < NIT; ++it) {
    if (it + 1 < NIT) {
      int kk = (it + 1) * 32;
      int nxt = cur ^ 1;
      gload16(gA + kk, sA[nxt] + w * 512);
      gload16(gB0 + kk, sB[nxt] + w * 512);
      gload16(gB1 + kk, sB[nxt] + 4096 + w * 512);
      asm volatile("s_waitcnt vmcnt(3)" ::: "memory");
    } else {
      asm volatile("s_waitcnt vmcnt(0)" ::: "memory");
    }
    __builtin_amdgcn_s_barrier();

    const uint16_t* pA = sA[cur];
    const uint16_t* pB = sB[cur];
    s8v af[4];
#pragma unroll
    for (int mi = 0; mi < 4; ++mi)
      af[mi] = *(const s8v*)(pA + (wr * 64 + mi * 16 + lrow) * 32 + lko);
#pragma unroll
    for (int ni = 0; ni < 4; ++ni) {
      s8v bf = *(const s8v*)(pB + (wc * 64 + ni * 16 + lrow) * 32 + lko);
#pragma unroll
      for (int mi = 0; mi < 4; ++mi)
        acc[mi][ni] = mfma_f16(af[mi], bf, acc[mi][ni]);
    }
    __builtin_amdgcn_s_barrier();
    cur ^= 1;
  }

  int rg = (lane >> 4) * 4;
#pragma unroll
  for (int mi = 0; mi < 4; ++mi) {
#pragma unroll
    for (int ni = 0; ni < 4; ++ni) {
      int col = wc * 64 + ni * 16 + (lane & 15);
#pragma unroll
      for (int r2 = 0; r2 < 4; ++r2) {
        long long row = bm + wr * 64 + mi * 16 + rg + r2;
        if (row < N_NODES) h[row * H1 + col] = acc[mi][ni][r2];  // STORE
      }
    }
  }
}

// ---------- aggregation 1: wave-per-node; final pass fuses bias+relu+fp16 pack ----------
__global__ __launch_bounds__(256) void k_agg1(
    const uint16_t* __restrict__ y1,   // fp16 chunk [MPAD][ldy]
    const int* __restrict__ es_src, const int* __restrict__ es_rel,
    const float* __restrict__ es_w, const int* __restrict__ rowptr,
    float* __restrict__ h, const float* __restrict__ b1,
    uint16_t* __restrict__ h16, int r0, int nb, int ldy, int fin) {
  int n = blockIdx.x * 4 + (threadIdx.x >> 6);
  int lane = threadIdx.x & 63;
  if (n >= N_NODES) return;
  int e0 = rowptr[n], e1 = rowptr[n + 1];
  int deg = e1 - e0;
  float4 acc = {0.f, 0.f, 0.f, 0.f};

  int mrel = -1000, msrc = 0;
  float mw = 0.f;
  if (lane < deg) {
    int e = e0 + lane;
    mrel = es_rel[e] - r0;
    msrc = es_src[e];
    mw = es_w[e];
  }
  int dcap = deg <= 64 ? deg : 64;
  for (int j = 0; j < dcap; ++j) {
    int off = __shfl(mrel, j);
    if ((unsigned)off < (unsigned)nb) {
      int s = __shfl(msrc, j);
      float wgt = __shfl(mw, j);
      uint2 v = *(const uint2*)(y1 + (long long)s * ldy + off * H1 + lane * 4);
      acc.x += wgt * h2f((uint16_t)v.x);
      acc.y += wgt * h2f((uint16_t)(v.x >> 16));
      acc.z += wgt * h2f((uint16_t)v.y);
      acc.w += wgt * h2f((uint16_t)(v.y >> 16));
    }
  }
  for (int e = e0 + 64; e < e1; ++e) {
    int off = es_rel[e] - r0;
    if ((unsigned)off < (unsigned)nb) {
      int s = es_src[e];
      float wgt = es_w[e];
      uint2 v = *(const uint2*)(y1 + (long long)s * ldy + off * H1 + lane * 4);
      acc.x += wgt * h2f((uint16_t)v.x);
      acc.y += wgt * h2f((uint16_t)(v.x >> 16));
      acc.z += wgt * h2f((uint16_t)v.y);
      acc.w += wgt * h2f((uint16_t)(v.y >> 16));
    }
  }
  float* hp = h + (long long)n * H1 + lane * 4;
  float4 old = *(const float4*)hp;
  old.x += acc.x; old.y += acc.y; old.z += acc.z; old.w += acc.w;
  if (fin) {
    float4 bv = *(const float4*)(b1 + lane * 4);
    float v0 = old.x + bv.x; v0 = v0 > 0.f ? v0 : 0.f;
    float v1 = old.y + bv.y; v1 = v1 > 0.f ? v1 : 0.f;
    float v2 = old.z + bv.z; v2 = v2 > 0.f ? v2 : 0.f;
    float v3 = old.w + bv.w; v3 = v3 > 0.f ? v3 : 0.f;
    uint2 o;
    o.x = (uint32_t)f2h(v0) | ((uint32_t)f2h(v1) << 16);
    o.y = (uint32_t)f2h(v2) | ((uint32_t)f2h(v3) << 16);
    *(uint2*)(h16 + (long long)n * H1 + lane * 4) = o;
  } else {
    *(float4*)hp = old;
  }
}

// ---------- layer-2 transform via MFMA (fp16): y2[M, 34] = h @ B2^T ----------
__global__ __launch_bounds__(256) void k_gemm2m(
    const uint16_t* __restrict__ h16, const uint16_t* __restrict__ b2h,
    float* __restrict__ y2) {
  __shared__ __align__(16) uint16_t sB[N2PAD * LDB2];
  __shared__ __align__(16) uint16_t sA[128 * 32];
  int tid = threadIdx.x, lane = tid & 63, w = tid >> 6;
  long long bm = (long long)blockIdx.x * 128;

  for (int cid = tid; cid < N2PAD * 32; cid += 256) {
    int row = cid >> 5, off = cid & 31;
    *(uint4*)(&sB[row * LDB2 + off * 8]) = *(const uint4*)(b2h + row * H1 + off * 8);
  }

  f4v zero = {0.f, 0.f, 0.f, 0.f};
  f4v acc[2][3];
#pragma unroll
  for (int i = 0; i < 2; ++i)
#pragma unroll
    for (int j = 0; j < 3; ++j) acc[i][j] = zero;

  int lrow = lane & 15;
  int lko = (((lane >> 4) ^ ((lane >> 1) & 3)) * 8);
  int srow0 = w * 32 + (lane >> 2), srow1 = srow0 + 16;
  int skel = (((lane & 3) ^ ((lane >> 3) & 3)) * 8);

  for (int kk = 0; kk < H1; kk += 32) {
    gload16(h16 + (bm + srow0) * H1 + kk + skel, sA + w * 1024);
    gload16(h16 + (bm + srow1) * H1 + kk + skel, sA + w * 1024 + 512);
    __syncthreads();

    s8v ah[2];
#pragma unroll
    for (int mi = 0; mi < 2; ++mi)
      ah[mi] = *(const s8v*)(sA + (w * 32 + mi * 16 + lrow) * 32 + lko);
#pragma unroll
    for (int nj = 0; nj < 3; ++nj) {
      s8v bh = *(const s8v*)(&sB[(nj * 16 + lrow) * LDB2 + kk + ((lane >> 4) * 8)]);
#pragma unroll
      for (int mi = 0; mi < 2; ++mi)
        acc[mi][nj] = mfma_f16(ah[mi], bh, acc[mi][nj]);
    }
    __syncthreads();
  }
  int rg = (lane >> 4) * 4;
#pragma unroll
  for (int mi = 0; mi < 2; ++mi) {
#pragma unroll
    for (int nj = 0; nj < 3; ++nj) {
      int col = nj * 16 + (lane & 15);
      if (col < Y2C) {
#pragma unroll
        for (int r2 = 0; r2 < 4; ++r2) {
          long long row = bm + w * 32 + mi * 16 + rg + r2;
          if (row < N_NODES) y2[row * Y2C + col] = acc[mi][nj][r2];
        }
      }
    }
  }
}

// ---------- aggregation 2 + tanh ----------
__global__ void k_agg2(const float* __restrict__ y2, const int* __restrict__ es_src,
                       const int* __restrict__ es_rel, const float* __restrict__ es_w,
                       const int* __restrict__ rowptr, const float* __restrict__ b2,
                       float* __restrict__ out) {
  int n = blockIdx.x * 4 + (threadIdx.x >> 6);
  int lane = threadIdx.x & 63;
  if (n >= N_NODES) return;
  float a0 = 0.f, a1 = 0.f;
  int e0 = rowptr[n], e1 = rowptr[n + 1];
  for (int e = e0 + lane; e < e1; e += 64) {
    int s = es_src[e], r = es_rel[e];
    float wgt = es_w[e];
    a0 += wgt * y2[s * Y2C + r * 2];
    a1 += wgt * y2[s * Y2C + r * 2 + 1];
  }
#pragma unroll
  for (int off = 32; off > 0; off >>= 1) {
    a0 += __shfl_down(a0, off);
    a1 += __shfl_down(a1, off);
  }
  if (lane == 0) {
    a0 += y2[n * Y2C + 2 * NREL] + b2[0];
    a1 += y2[n * Y2C + 2 * NREL + 1] + b2[1];
    out[n * 2] = tanhf(a0);
    out[n * 2 + 1] = tanhf(a1);
  }
}

extern "C" void kernel_launch(void* const* d_in, const int* in_sizes, int n_in,
                              void* d_out, int out_size, void* d_ws, size_t ws_size,
                              hipStream_t stream) {
  const float* x     = (const float*)d_in[0];
  const int*   ei    = (const int*)d_in[1];
  const int*   et    = (const int*)d_in[2];
  const float* W1    = (const float*)d_in[3];
  const float* root1 = (const float*)d_in[4];
  const float* b1    = (const float*)d_in[5];
  const float* W2    = (const float*)d_in[6];
  const float* root2 = (const float*)d_in[7];
  const float* b2    = (const float*)d_in[8];
  const int E = in_sizes[2];
  const int* src = ei;
  const int* dst = ei + E;

  char* ws = (char*)d_ws;
  size_t off = 0;
  auto alloc = [&](size_t bytes) {
    size_t o = off; off += (bytes + 255) & ~(size_t)255; return o;
  };
  // zero region: only cnt/deg/cur now (h is fully stored by k_gemmroot)
  size_t o_cnt = alloc((size_t)NREL * N_NODES * 4);
  size_t o_deg = alloc((size_t)(N_NODES + 1) * 4);
  size_t o_cur = alloc((size_t)N_NODES * 4);
  size_t zero_bytes = off;
  size_t o_h   = alloc((size_t)N_NODES * H1 * 4);
  size_t o_rp   = alloc((size_t)(N_NODES + 1) * 4);
  size_t o_bsum = alloc(64 * 4);
  size_t o_bscn = alloc(64 * 4);
  size_t o_esrc = alloc((size_t)E * 4);
  size_t o_erel = alloc((size_t)E * 4);
  size_t o_ew   = alloc((size_t)E * 4);
  size_t o_xh   = alloc((size_t)MPAD * KPAD * 2);   // h16 aliases this later
  size_t o_b1h  = alloc((size_t)NCOL1 * KPAD * 2);
  size_t o_b2h  = alloc((size_t)N2PAD * H1 * 2);
  size_t o_y2   = alloc((size_t)N_NODES * Y2C * 4);
  size_t o_y1   = off;  // rest of ws: y1 chunk buffer (fp16)

  int*      cnt  = (int*)(ws + o_cnt);
  int*      deg  = (int*)(ws + o_deg);
  int*      cur  = (int*)(ws + o_cur);
  float*    h    = (float*)(ws + o_h);
  int*      rp   = (int*)(ws + o_rp);
  int*      bsum = (int*)(ws + o_bsum);
  int*      bscn = (int*)(ws + o_bscn);
  int*      esrc = (int*)(ws + o_esrc);
  int*      erel = (int*)(ws + o_erel);
  float*    ew   = (float*)(ws + o_ew);
  uint16_t* xh   = (uint16_t*)(ws + o_xh);
  uint16_t* b1h  = (uint16_t*)(ws + o_b1h);
  uint16_t* b2h  = (uint16_t*)(ws + o_b2h);
  // h16 aliases xh: xh dead after last GEMM; final k_agg1 writes h16 strictly later.
  uint16_t* h16  = (uint16_t*)(ws + o_xh);
  float*    y2   = (float*)(ws + o_y2);
  uint16_t* y1   = (uint16_t*)(ws + o_y1);

  size_t per_block = (size_t)MPAD * H1 * 2;  // one 256-col fp16 y1 block
  int G = 1;
  if (ws_size > o_y1 + per_block) {
    size_t g = (ws_size - o_y1) / per_block;
    G = (int)(g > (size_t)NBREL ? (size_t)NBREL : g);
  }
  int npass = (NBREL + G - 1) / G;
  int Gb = (NBREL + npass - 1) / npass;   // balanced pass sizes

  const int NSB = (N_NODES + 1023) / 1024;

  hipMemsetAsync(ws, 0, zero_bytes, stream);
  k_count<<<(E + 255) / 256, 256, 0, stream>>>(dst, et, deg, cnt, E);
  k_s1<<<NSB, 1024, 0, stream>>>(deg, rp, bsum);
  k_s2<<<1, 64, 0, stream>>>(bsum, bscn, rp, NSB);
  k_s3<<<NSB, 1024, 0, stream>>>(bscn, rp);
  k_scatter<<<(E + 255) / 256, 256, 0, stream>>>(src, dst, et, rp, cur, cnt,
                                                 esrc, erel, ew, E);
  k_pack_x<<<(unsigned)(((long long)MPAD * (KPAD / 2) + 255) / 256), 256, 0, stream>>>(x, xh);
  k_pack_b1<<<(unsigned)(((long long)NCOL1 * KPAD + 255) / 256), 256, 0, stream>>>(W1, root1, b1h);
  k_pack_b2<<<(N2PAD * H1 + 255) / 256, 256, 0, stream>>>(W2, root2, b2h);

  // root contribution STORES h (no memset/read of h needed)
  k_gemmroot<<<MPAD / 128, 512, 0, stream>>>(xh, b1h + (size_t)NREL * H1 * KPAD, h);

  int r0 = 0;
  for (int p = 0; p < npass; ++p) {
    int nb = (NBREL - r0 < Gb) ? (NBREL - r0) : Gb;
    int nwg = (MPAD / 128) * nb;           // col-tiles of 256 = nb
    k_gemm1<<<nwg, 256, 0, stream>>>(xh, b1h + (size_t)r0 * H1 * KPAD, y1, nb * H1);
    k_agg1<<<(N_NODES + 3) / 4, 256, 0, stream>>>(y1, esrc, erel, ew, rp, h, b1,
                                                  h16, r0, nb, nb * H1,
                                                  (p == npass - 1) ? 1 : 0);
    r0 += nb;
  }
  k_gemm2m<<<MPAD / 128, 256, 0, stream>>>(h16, b2h, y2);
  k_agg2<<<(N_NODES + 3) / 4, 256, 0, stream>>>(y2, esrc, erel, ew, rp, b2,
                                                (float*)d_out);
  (void)n_in; (void)out_size;
}